// Round 7
// baseline (120.751 us; speedup 1.0000x reference)
//
#include <hip/hip_runtime.h>
#include <hip/hip_bf16.h>

// Problem constants
#define B_SZ   16384
#define D_SZ   768
#define H_SZ   128
#define S_SZ   65536
#define E_SZ   7

// Packed GEMM geometry (logical K/N spaces; B stored frag-major, see pack kernel)
// K layout: [0,768) h_t | [768,896) s_t | [896,1664) h_ctx | 1664..1666 sent | 1667 bias(1.0) | pad->1696
// N layout: [0,256) r,z (gi+gh summed) | [256,384) i_n | [384,512) h_n | [512,519) W_e | 519 W_s | pad->528
// Frag K-activity: [0,16) rz: h_t+s_t+tail | [16,24) i_n: h_t+tail | [24,32) h_n: s_t+tail | 32 heads: all
#define NFR    33      // N fragments of 16
#define NSTEP  53      // K steps of 32: 24 (h_t) + 4 (s_t) + 24 (h_ctx) + 1 (tail)

typedef __attribute__((ext_vector_type(8))) short bf16x8;
typedef __attribute__((ext_vector_type(4))) float f32x4;

#define LD4(p) (*reinterpret_cast<const float4*>(p))

static __device__ __forceinline__ ushort f2bf(float v) {
    unsigned u = __float_as_uint(v);
    u = (u + 0x7FFFu + ((u >> 16) & 1u)) >> 16;   // RNE (pack kernel / tail only)
    return (ushort)u;
}

// pack two floats -> two bf16 (round-half-up) in one u32 via v_perm
static __device__ __forceinline__ unsigned pk2(float x, float y) {
    unsigned a = __float_as_uint(x) + 0x8000u;
    unsigned b = __float_as_uint(y) + 0x8000u;
    return __builtin_amdgcn_perm(b, a, 0x07060302);   // [a.hi16 | b.hi16]
}

static __device__ __forceinline__ bf16x8 cvt8(float4 a, float4 b) {
    union { unsigned u[4]; bf16x8 v; } r;
    r.u[0] = pk2(a.x, a.y); r.u[1] = pk2(a.z, a.w);
    r.u[2] = pk2(b.x, b.y); r.u[3] = pk2(b.z, b.w);
    return r.v;
}

// logical packed-weight value at (n, k)
static __device__ __forceinline__ float w2_value(int n, int k,
    const float* __restrict__ W_ih, const float* __restrict__ W_hh,
    const float* __restrict__ b_ih, const float* __restrict__ b_hh,
    const float* __restrict__ W_e,  const float* __restrict__ b_e,
    const float* __restrict__ W_s,  const float* __restrict__ b_s)
{
    float v = 0.0f;
    if (n < 256) {                       // r,z rows: gi + gh summed
        if (k < 768)                        v = W_ih[(size_t)n * 771 + k];
        else if (k < 896)                   v = W_hh[(size_t)n * 128 + (k - 768)];
        else if (k >= 1664 && k < 1667)     v = W_ih[(size_t)n * 771 + 768 + (k - 1664)];
        else if (k == 1667)                 v = b_ih[n] + b_hh[n];
    } else if (n < 384) {                // i_n rows (W_ih rows 256..383)
        if (k < 768)                        v = W_ih[(size_t)n * 771 + k];
        else if (k >= 1664 && k < 1667)     v = W_ih[(size_t)n * 771 + 768 + (k - 1664)];
        else if (k == 1667)                 v = b_ih[n];
    } else if (n < 512) {                // h_n rows (W_hh rows 256..383)
        int g = n - 128;
        if (k >= 768 && k < 896)            v = W_hh[(size_t)g * 128 + (k - 768)];
        else if (k == 1667)                 v = b_hh[g];
    } else if (n < 520) {                // heads: z_t = [h_t(0:768) sent(768:771) s_t(771:899) h_ctx(899:1667)]
        int e = n - 512;
        const float* Wr = (e < E_SZ) ? (W_e + (size_t)e * 1667) : W_s;
        if (k < 768)                        v = Wr[k];
        else if (k < 896)                   v = Wr[771 + (k - 768)];
        else if (k < 1664)                  v = Wr[899 + (k - 896)];
        else if (k < 1667)                  v = Wr[768 + (k - 1664)];
        else if (k == 1667)                 v = (e < E_SZ) ? b_e[e] : b_s[0];
    }
    return v;
}

// ---------------- pack W2 frag-major: W2f[(nf*NSTEP + kstep)*64 + lane][8] ----------------
__global__ __launch_bounds__(256) void pack_w2f_kernel(
    const float* __restrict__ W_ih, const float* __restrict__ W_hh,
    const float* __restrict__ b_ih, const float* __restrict__ b_hh,
    const float* __restrict__ W_e,  const float* __restrict__ b_e,
    const float* __restrict__ W_s,  const float* __restrict__ b_s,
    ushort* __restrict__ W2f)
{
    int tid = blockIdx.x * 256 + threadIdx.x;
    if (tid >= NFR * NSTEP * 64) return;
    int lane  = tid & 63;
    int kstep = (tid >> 6) % NSTEP;
    int nf    = tid / (NSTEP * 64);
    int n     = nf * 16 + (lane & 15);
    int kbase = kstep * 32 + (lane >> 4) * 8;
    ushort o[8];
#pragma unroll
    for (int j = 0; j < 8; ++j)
        o[j] = f2bf(w2_value(n, kbase + j, W_ih, W_hh, b_ih, b_hh, W_e, b_e, W_s, b_s));
    *reinterpret_cast<uint4*>(W2f + (size_t)tid * 8) = *reinterpret_cast<const uint4*>(o);
}

// ---------------- winner (last-write-wins) ----------------
__global__ __launch_bounds__(256) void winner_kernel(const int* __restrict__ slot_ids,
                                                     int* __restrict__ winner)
{
    int b = blockIdx.x * 256 + threadIdx.x;
    if (b < B_SZ) atomicMax(&winner[slot_ids[b]], b);
}

static __device__ __forceinline__ bf16x8 ldB(const ushort* __restrict__ W2f, int nf, int ks, int lane) {
    return *reinterpret_cast<const bf16x8*>(W2f + ((size_t)(nf * NSTEP + ks) * 64 + lane) * 8);
}

// one B-frag -> two MFMAs (rowgroup0 with a0, rowgroup1 with a1)
#define MM(nf_, loc_, ks_) do {                                                        \
        bf16x8 bb = ldB(W2f, (nf_), (ks_), lane);                                      \
        acc[(loc_)]        = __builtin_amdgcn_mfma_f32_16x16x32_bf16(a0, bb, acc[(loc_)], 0, 0, 0);        \
        acc[NLOC + (loc_)] = __builtin_amdgcn_mfma_f32_16x16x32_bf16(a1, bb, acc[NLOC + (loc_)], 0, 0, 0); \
    } while (0)

// ---------------- per-wave compute over assigned frags, M=32 (two rowgroups) ----------------
template<int RZ0,int RZ1,int IN0,int IN1,int HN0,int HN1,int HD>
static __device__ __forceinline__ void wave_compute(
    const float* __restrict__ h_t, const float* __restrict__ h_ctx,
    const float* __restrict__ sent, const float* __restrict__ memory,
    const int* __restrict__ slot_ids, int row0, int lane,
    const ushort* __restrict__ W2f, f32x4* __restrict__ acc)
{
    constexpr int NRZ = RZ1 - RZ0, NIN = IN1 - IN0, NHN = HN1 - HN0;
    constexpr int NLOC = NRZ + NIN + NHN + HD;
    const int col = lane & 15, kg = lane >> 4;
    const int rA0 = row0 + col, rA1 = rA0 + 16;

#pragma unroll
    for (int i = 0; i < 2 * NLOC; ++i) { f32x4 z = {0.f,0.f,0.f,0.f}; acc[i] = z; }

    // h_t: steps 0..23 — rz, i_n, heads
    {
        const float* p0 = h_t + (size_t)rA0 * D_SZ + kg * 8;
        const float* p1 = h_t + (size_t)rA1 * D_SZ + kg * 8;
#pragma unroll 2
        for (int s = 0; s < 24; ++s) {
            bf16x8 a0 = cvt8(LD4(p0 + s * 32), LD4(p0 + s * 32 + 4));
            bf16x8 a1 = cvt8(LD4(p1 + s * 32), LD4(p1 + s * 32 + 4));
#pragma unroll
            for (int i = 0; i < NRZ; ++i) MM(RZ0 + i, i, s);
#pragma unroll
            for (int i = 0; i < NIN; ++i) MM(IN0 + i, NRZ + i, s);
            if constexpr (HD) MM(32, NLOC - 1, s);
        }
    }
    // s_t: steps 24..27 — rz, h_n, heads (gather)
    {
        const int sl0 = slot_ids[rA0], sl1 = slot_ids[rA1];
        const float* p0 = memory + (size_t)sl0 * H_SZ + kg * 8;
        const float* p1 = memory + (size_t)sl1 * H_SZ + kg * 8;
#pragma unroll
        for (int t = 0; t < 4; ++t) {
            bf16x8 a0 = cvt8(LD4(p0 + t * 32), LD4(p0 + t * 32 + 4));
            bf16x8 a1 = cvt8(LD4(p1 + t * 32), LD4(p1 + t * 32 + 4));
#pragma unroll
            for (int i = 0; i < NRZ; ++i) MM(RZ0 + i, i, 24 + t);
#pragma unroll
            for (int i = 0; i < NHN; ++i) MM(HN0 + i, NRZ + NIN + i, 24 + t);
            if constexpr (HD) MM(32, NLOC - 1, 24 + t);
        }
    }
    // h_ctx: steps 28..51 — heads only
    if constexpr (HD) {
        const float* p0 = h_ctx + (size_t)rA0 * D_SZ + kg * 8;
        const float* p1 = h_ctx + (size_t)rA1 * D_SZ + kg * 8;
#pragma unroll 2
        for (int t = 0; t < 24; ++t) {
            bf16x8 a0 = cvt8(LD4(p0 + t * 32), LD4(p0 + t * 32 + 4));
            bf16x8 a1 = cvt8(LD4(p1 + t * 32), LD4(p1 + t * 32 + 4));
            MM(32, NLOC - 1, 28 + t);
        }
    }
    // tail (step 52): sent(3) + bias-one + zeros — all owned frags
    {
        bf16x8 a0, a1;
#pragma unroll
        for (int j = 0; j < 8; ++j) {
            int kk = kg * 8 + j;
            float v0 = 0.0f, v1 = 0.0f;
            if (kk < 3)       { v0 = sent[(size_t)rA0 * 3 + kk]; v1 = sent[(size_t)rA1 * 3 + kk]; }
            else if (kk == 3) { v0 = 1.0f; v1 = 1.0f; }
            a0[j] = (short)f2bf(v0); a1[j] = (short)f2bf(v1);
        }
#pragma unroll
        for (int i = 0; i < NRZ; ++i) MM(RZ0 + i, i, 52);
#pragma unroll
        for (int i = 0; i < NIN; ++i) MM(IN0 + i, NRZ + i, 52);
#pragma unroll
        for (int i = 0; i < NHN; ++i) MM(HN0 + i, NRZ + NIN + i, 52);
        if constexpr (HD) MM(32, NLOC - 1, 52);
    }
}

// ---------------- dump one rowgroup's partials to LDS ----------------
template<int RZ0,int RZ1,int IN0,int IN1,int HN0,int HN1,int HD,int RG>
static __device__ __forceinline__ void dump_rg(const f32x4* __restrict__ acc, int lane,
                                               f32x4* __restrict__ red)
{
    constexpr int NRZ = RZ1 - RZ0, NIN = IN1 - IN0, NHN = HN1 - HN0;
    constexpr int NLOC = NRZ + NIN + NHN + HD;
    constexpr int O = RG * NLOC;
#pragma unroll
    for (int i = 0; i < NRZ; ++i) red[(RZ0 + i) * 64 + lane] = acc[O + i];
#pragma unroll
    for (int i = 0; i < NIN; ++i) red[(IN0 + i) * 64 + lane] = acc[O + NRZ + i];
#pragma unroll
    for (int i = 0; i < NHN; ++i) red[(HN0 + i) * 64 + lane] = acc[O + NRZ + NIN + i];
    if constexpr (HD) red[32 * 64 + lane] = acc[O + NLOC - 1];
}

#define WAVE_DISPATCH(FN, ...) do {                                              \
        switch (wave) {                                                          \
        case 0: FN<0,2,16,17,24,25,0 __VA_ARGS__>(ARGS); break;                  \
        case 1: FN<2,4,17,18,25,26,0 __VA_ARGS__>(ARGS); break;                  \
        case 2: FN<4,6,18,19,26,27,0 __VA_ARGS__>(ARGS); break;                  \
        case 3: FN<6,8,19,20,27,28,0 __VA_ARGS__>(ARGS); break;                  \
        case 4: FN<8,10,20,21,28,29,0 __VA_ARGS__>(ARGS); break;                 \
        case 5: FN<10,12,21,22,29,30,0 __VA_ARGS__>(ARGS); break;                \
        case 6: FN<12,14,22,24,30,31,0 __VA_ARGS__>(ARGS); break;                \
        default: FN<14,16,16,16,31,32,1 __VA_ARGS__>(ARGS); break;               \
        }                                                                        \
    } while (0)

// ---------------- fused GEMM (8-wave N-split, M=32) + shared epilogue ----------------
__global__ __launch_bounds__(512, 4) void fused_kernel(
    const float* __restrict__ h_t,   const float* __restrict__ h_ctx,
    const float* __restrict__ sent,  const int* __restrict__ slot_ids,
    const float* __restrict__ memory,const ushort* __restrict__ W2f,
    const int* __restrict__ winner,
    float* __restrict__ out_emo, float* __restrict__ out_shift, float* __restrict__ out_mem)
{
    __shared__ alignas(16) f32x4 red[NFR * 64];   // 33.8 KB, reused for both rowgroups

    const int tid  = threadIdx.x;
    const int wave = tid >> 6;
    const int lane = tid & 63;
    const int row0 = blockIdx.x * 32;

    f32x4 acc[10];
    {
#define ARGS h_t, h_ctx, sent, memory, slot_ids, row0, lane, W2f, acc
        WAVE_DISPATCH(wave_compute);
#undef ARGS
    }

    // ---- rowgroup 0: dump -> epilogue rows [row0, row0+16) ----
    {
#define ARGS acc, lane, red
        WAVE_DISPATCH(dump_rg, , 0);
#undef ARGS
    }
    __syncthreads();

#define EPILOGUE(P) do {                                                                \
        if (tid < 256) {                                                                \
            const int erow = tid >> 4, ecol = tid & 15;                                 \
            const int grow = row0 + (P) * 16 + erow;                                    \
            const int li   = (erow >> 2) * 16 + ecol;                                   \
            const int rsel = erow & 3;                                                  \
            const int slot = slot_ids[grow];                                            \
            const bool win = (winner[slot] == grow);                                    \
            _Pragma("unroll")                                                           \
            for (int q = 0; q < 8; ++q) {                                               \
                float rg  = red[q * 64 + li][rsel];                                     \
                float zg  = red[(8 + q) * 64 + li][rsel];                               \
                float inn = red[(16 + q) * 64 + li][rsel];                              \
                float hnn = red[(24 + q) * 64 + li][rsel];                              \
                rg = 1.0f / (1.0f + __expf(-rg));                                       \
                zg = 1.0f / (1.0f + __expf(-zg));                                       \
                float nn = tanhf(inn + rg * hnn);                                       \
                float h  = memory[(size_t)slot * H_SZ + q * 16 + ecol];                 \
                float sn = (1.0f - zg) * nn + zg * h;                                   \
                if (win) out_mem[(size_t)slot * H_SZ + q * 16 + ecol] = sn;             \
            }                                                                           \
            float hv = red[32 * 64 + li][rsel];                                         \
            if (ecol < E_SZ)       out_emo[(size_t)grow * E_SZ + ecol] = hv;            \
            else if (ecol == E_SZ) out_shift[grow] = hv;                                \
        }                                                                               \
    } while (0)

    EPILOGUE(0);
    __syncthreads();

    // ---- rowgroup 1: dump -> epilogue rows [row0+16, row0+32) ----
    {
#define ARGS acc, lane, red
        WAVE_DISPATCH(dump_rg, , 1);
#undef ARGS
    }
    __syncthreads();

    EPILOGUE(1);
#undef EPILOGUE
}

// ---------------- launch ----------------
extern "C" void kernel_launch(void* const* d_in, const int* in_sizes, int n_in,
                              void* d_out, int out_size, void* d_ws, size_t ws_size,
                              hipStream_t stream)
{
    const float* h_t     = (const float*)d_in[0];
    const float* h_ctx   = (const float*)d_in[1];
    const float* sent    = (const float*)d_in[2];
    const int*   slot_ids= (const int*)  d_in[3];
    const float* memory  = (const float*)d_in[4];
    const float* W_ih    = (const float*)d_in[5];
    const float* W_hh    = (const float*)d_in[6];
    const float* b_ih    = (const float*)d_in[7];
    const float* b_hh    = (const float*)d_in[8];
    const float* W_e     = (const float*)d_in[9];
    const float* b_e     = (const float*)d_in[10];
    const float* W_s     = (const float*)d_in[11];
    const float* b_s     = (const float*)d_in[12];

    float* out       = (float*)d_out;
    float* out_emo   = out;                                    // [B,7]
    float* out_shift = out + (size_t)B_SZ * E_SZ;              // [B]
    float* out_mem   = out + (size_t)B_SZ * E_SZ + B_SZ;       // [S,H]

    int*    winner = (int*)d_ws;                               // S ints
    ushort* W2f    = (ushort*)((char*)d_ws + (size_t)S_SZ * sizeof(int));

    hipMemsetAsync(winner, 0xFF, (size_t)S_SZ * sizeof(int), stream);   // -1
    hipMemcpyAsync(out_mem, memory, (size_t)S_SZ * H_SZ * sizeof(float),
                   hipMemcpyDeviceToDevice, stream);

    pack_w2f_kernel<<<(NFR * NSTEP * 64 + 255) / 256, 256, 0, stream>>>(
        W_ih, W_hh, b_ih, b_hh, W_e, b_e, W_s, b_s, W2f);
    winner_kernel<<<B_SZ / 256, 256, 0, stream>>>(slot_ids, winner);
    fused_kernel<<<B_SZ / 32, 512, 0, stream>>>(
        h_t, h_ctx, sent, slot_ids, memory, W2f, winner, out_emo, out_shift, out_mem);
}

// Round 8
// 120.555 us; speedup vs baseline: 1.0016x; 1.0016x over previous
//
#include <hip/hip_runtime.h>
#include <hip/hip_bf16.h>

// Problem constants
#define B_SZ   16384
#define D_SZ   768
#define H_SZ   128
#define S_SZ   65536
#define E_SZ   7

// Packed GEMM geometry (logical K/N spaces; B stored frag-major, see pack kernel)
// K layout: [0,768) h_t | [768,896) s_t | [896,1664) h_ctx | 1664..1666 sent | 1667 bias(1.0) | pad->1696
// N layout: [0,256) r,z (gi+gh summed) | [256,384) i_n | [384,512) h_n | [512,519) W_e | 519 W_s | pad->528
// Frag K-activity: [0,16) rz: h_t+s_t+tail | [16,24) i_n: h_t+tail | [24,32) h_n: s_t+tail | 32 heads: all
// Wave w (of 8): rz {2w,2w+1}, i_n 16+w, h_n 24+w, + heads K-slice HSL[w]..HSL[w+1]  => 94-95 units/wave
#define NFR    33      // N fragments of 16
#define NSTEP  53      // K steps of 32: 24 (h_t) + 4 (s_t) + 24 (h_ctx) + 1 (tail)

typedef __attribute__((ext_vector_type(8))) short bf16x8;
typedef __attribute__((ext_vector_type(4))) float f32x4;

#define LD4(p) (*reinterpret_cast<const float4*>(p))
#define MFMA(d, a, b) d = __builtin_amdgcn_mfma_f32_16x16x32_bf16(a, b, d, 0, 0, 0)

static __device__ __forceinline__ ushort f2bf(float v) {
    unsigned u = __float_as_uint(v);
    u = (u + 0x7FFFu + ((u >> 16) & 1u)) >> 16;   // RNE (pack kernel / tail only)
    return (ushort)u;
}

// pack two floats -> two bf16 (round-half-up) in one u32 via v_perm
static __device__ __forceinline__ unsigned pk2(float x, float y) {
    unsigned a = __float_as_uint(x) + 0x8000u;
    unsigned b = __float_as_uint(y) + 0x8000u;
    return __builtin_amdgcn_perm(b, a, 0x07060302);   // [a.hi16 | b.hi16]
}

static __device__ __forceinline__ bf16x8 cvt8(float4 a, float4 b) {
    union { unsigned u[4]; bf16x8 v; } r;
    r.u[0] = pk2(a.x, a.y); r.u[1] = pk2(a.z, a.w);
    r.u[2] = pk2(b.x, b.y); r.u[3] = pk2(b.z, b.w);
    return r.v;
}

// logical packed-weight value at (n, k)
static __device__ __forceinline__ float w2_value(int n, int k,
    const float* __restrict__ W_ih, const float* __restrict__ W_hh,
    const float* __restrict__ b_ih, const float* __restrict__ b_hh,
    const float* __restrict__ W_e,  const float* __restrict__ b_e,
    const float* __restrict__ W_s,  const float* __restrict__ b_s)
{
    float v = 0.0f;
    if (n < 256) {                       // r,z rows: gi + gh summed
        if (k < 768)                        v = W_ih[(size_t)n * 771 + k];
        else if (k < 896)                   v = W_hh[(size_t)n * 128 + (k - 768)];
        else if (k >= 1664 && k < 1667)     v = W_ih[(size_t)n * 771 + 768 + (k - 1664)];
        else if (k == 1667)                 v = b_ih[n] + b_hh[n];
    } else if (n < 384) {                // i_n rows (W_ih rows 256..383)
        if (k < 768)                        v = W_ih[(size_t)n * 771 + k];
        else if (k >= 1664 && k < 1667)     v = W_ih[(size_t)n * 771 + 768 + (k - 1664)];
        else if (k == 1667)                 v = b_ih[n];
    } else if (n < 512) {                // h_n rows (W_hh rows 256..383)
        int g = n - 128;
        if (k >= 768 && k < 896)            v = W_hh[(size_t)g * 128 + (k - 768)];
        else if (k == 1667)                 v = b_hh[g];
    } else if (n < 520) {                // heads: z_t = [h_t(0:768) sent(768:771) s_t(771:899) h_ctx(899:1667)]
        int e = n - 512;
        const float* Wr = (e < E_SZ) ? (W_e + (size_t)e * 1667) : W_s;
        if (k < 768)                        v = Wr[k];
        else if (k < 896)                   v = Wr[771 + (k - 768)];
        else if (k < 1664)                  v = Wr[899 + (k - 896)];
        else if (k < 1667)                  v = Wr[768 + (k - 1664)];
        else if (k == 1667)                 v = (e < E_SZ) ? b_e[e] : b_s[0];
    }
    return v;
}

// ---------------- pack W2 frag-major: W2f[(nf*NSTEP + kstep)*64 + lane][8] ----------------
__global__ __launch_bounds__(256) void pack_w2f_kernel(
    const float* __restrict__ W_ih, const float* __restrict__ W_hh,
    const float* __restrict__ b_ih, const float* __restrict__ b_hh,
    const float* __restrict__ W_e,  const float* __restrict__ b_e,
    const float* __restrict__ W_s,  const float* __restrict__ b_s,
    ushort* __restrict__ W2f)
{
    int tid = blockIdx.x * 256 + threadIdx.x;
    if (tid >= NFR * NSTEP * 64) return;
    int lane  = tid & 63;
    int kstep = (tid >> 6) % NSTEP;
    int nf    = tid / (NSTEP * 64);
    int n     = nf * 16 + (lane & 15);
    int kbase = kstep * 32 + (lane >> 4) * 8;
    ushort o[8];
#pragma unroll
    for (int j = 0; j < 8; ++j)
        o[j] = f2bf(w2_value(n, kbase + j, W_ih, W_hh, b_ih, b_hh, W_e, b_e, W_s, b_s));
    *reinterpret_cast<uint4*>(W2f + (size_t)tid * 8) = *reinterpret_cast<const uint4*>(o);
}

// ---------------- winner (last-write-wins) ----------------
__global__ __launch_bounds__(256) void winner_kernel(const int* __restrict__ slot_ids,
                                                     int* __restrict__ winner)
{
    int b = blockIdx.x * 256 + threadIdx.x;
    if (b < B_SZ) atomicMax(&winner[slot_ids[b]], b);
}

static __device__ __forceinline__ bf16x8 ldB(const ushort* __restrict__ W2f, int nf, int ks, int lane) {
    return *reinterpret_cast<const bf16x8*>(W2f + ((size_t)(nf * NSTEP + ks) * 64 + lane) * 8);
}

// heads A-source select; branches fold at compile time under full unroll
static __device__ __forceinline__ void heads_A(
    int s, int rA0, int rA1, int sl0, int sl1, int kg,
    const float* __restrict__ h_t, const float* __restrict__ h_ctx,
    const float* __restrict__ memory, const float* __restrict__ sent,
    float4& a00, float4& a01, float4& a10, float4& a11)
{
    if (s < 24) {
        const float* p0 = h_t + (size_t)rA0 * D_SZ + s * 32 + kg * 8;
        const float* p1 = h_t + (size_t)rA1 * D_SZ + s * 32 + kg * 8;
        a00 = LD4(p0); a01 = LD4(p0 + 4); a10 = LD4(p1); a11 = LD4(p1 + 4);
    } else if (s < 28) {
        const float* p0 = memory + (size_t)sl0 * H_SZ + (s - 24) * 32 + kg * 8;
        const float* p1 = memory + (size_t)sl1 * H_SZ + (s - 24) * 32 + kg * 8;
        a00 = LD4(p0); a01 = LD4(p0 + 4); a10 = LD4(p1); a11 = LD4(p1 + 4);
    } else if (s < 52) {
        const float* p0 = h_ctx + (size_t)rA0 * D_SZ + (s - 28) * 32 + kg * 8;
        const float* p1 = h_ctx + (size_t)rA1 * D_SZ + (s - 28) * 32 + kg * 8;
        a00 = LD4(p0); a01 = LD4(p0 + 4); a10 = LD4(p1); a11 = LD4(p1 + 4);
    } else {
        float4 z = {0.f, 0.f, 0.f, 0.f};
        a00 = z; a01 = z; a10 = z; a11 = z;
        if (kg == 0) {
            a00.x = sent[(size_t)rA0 * 3]; a00.y = sent[(size_t)rA0 * 3 + 1];
            a00.z = sent[(size_t)rA0 * 3 + 2]; a00.w = 1.0f;
            a10.x = sent[(size_t)rA1 * 3]; a10.y = sent[(size_t)rA1 * 3 + 1];
            a10.z = sent[(size_t)rA1 * 3 + 2]; a10.w = 1.0f;
        }
    }
}

// ---------------- per-wave compute: 2 rz + 1 i_n + 1 h_n frags + heads K-slice ----------------
// acc[0..3] = rowgroup0 {rza, rzb, in, hn}; acc[4..7] = rowgroup1; hacc[rg] = heads partial
template<int W>
static __device__ __forceinline__ void wave_compute(
    const float* __restrict__ h_t, const float* __restrict__ h_ctx,
    const float* __restrict__ sent, const float* __restrict__ memory,
    const int* __restrict__ slot_ids, int row0, int lane,
    const ushort* __restrict__ W2f, f32x4* __restrict__ acc, f32x4* __restrict__ hacc)
{
    constexpr int RZa = 2 * W, RZb = 2 * W + 1, INf = 16 + W, HNf = 24 + W;
    constexpr int HSL[9] = {0, 7, 14, 21, 28, 34, 40, 46, 53};
    constexpr int HS0 = HSL[W], HS1 = HSL[W + 1];

    const int col = lane & 15, kg = lane >> 4;
    const int rA0 = row0 + col, rA1 = rA0 + 16;
    const int sl0 = slot_ids[rA0], sl1 = slot_ids[rA1];

    {
        f32x4 z = {0.f, 0.f, 0.f, 0.f};
#pragma unroll
        for (int i = 0; i < 8; ++i) acc[i] = z;
    }

    // ---- h_t phase: steps 0..23, frags rza,rzb,in (2-deep explicit pipeline) ----
    {
        const float* p0 = h_t + (size_t)rA0 * D_SZ + kg * 8;
        const float* p1 = h_t + (size_t)rA1 * D_SZ + kg * 8;
        float4 A00 = LD4(p0), A01 = LD4(p0 + 4), A10 = LD4(p1), A11 = LD4(p1 + 4);
        bf16x8 B0 = ldB(W2f, RZa, 0, lane), B1 = ldB(W2f, RZb, 0, lane), B2 = ldB(W2f, INf, 0, lane);
#pragma unroll
        for (int s = 0; s < 24; ++s) {
            float4 N00, N01, N10, N11; bf16x8 Nb0, Nb1, Nb2;
            if (s < 23) {
                N00 = LD4(p0 + (s + 1) * 32); N01 = LD4(p0 + (s + 1) * 32 + 4);
                N10 = LD4(p1 + (s + 1) * 32); N11 = LD4(p1 + (s + 1) * 32 + 4);
                Nb0 = ldB(W2f, RZa, s + 1, lane);
                Nb1 = ldB(W2f, RZb, s + 1, lane);
                Nb2 = ldB(W2f, INf, s + 1, lane);
            }
            bf16x8 a0 = cvt8(A00, A01), a1 = cvt8(A10, A11);
            MFMA(acc[0], a0, B0); MFMA(acc[4], a1, B0);
            MFMA(acc[1], a0, B1); MFMA(acc[5], a1, B1);
            MFMA(acc[2], a0, B2); MFMA(acc[6], a1, B2);
            if (s < 23) { A00 = N00; A01 = N01; A10 = N10; A11 = N11; B0 = Nb0; B1 = Nb1; B2 = Nb2; }
        }
    }
    // ---- s_t phase: steps 24..27, frags rza,rzb,hn (gather) ----
    {
        const float* p0 = memory + (size_t)sl0 * H_SZ + kg * 8;
        const float* p1 = memory + (size_t)sl1 * H_SZ + kg * 8;
        float4 A00 = LD4(p0), A01 = LD4(p0 + 4), A10 = LD4(p1), A11 = LD4(p1 + 4);
        bf16x8 B0 = ldB(W2f, RZa, 24, lane), B1 = ldB(W2f, RZb, 24, lane), B2 = ldB(W2f, HNf, 24, lane);
#pragma unroll
        for (int t = 0; t < 4; ++t) {
            float4 N00, N01, N10, N11; bf16x8 Nb0, Nb1, Nb2;
            if (t < 3) {
                N00 = LD4(p0 + (t + 1) * 32); N01 = LD4(p0 + (t + 1) * 32 + 4);
                N10 = LD4(p1 + (t + 1) * 32); N11 = LD4(p1 + (t + 1) * 32 + 4);
                Nb0 = ldB(W2f, RZa, 25 + t, lane);
                Nb1 = ldB(W2f, RZb, 25 + t, lane);
                Nb2 = ldB(W2f, HNf, 25 + t, lane);
            }
            bf16x8 a0 = cvt8(A00, A01), a1 = cvt8(A10, A11);
            MFMA(acc[0], a0, B0); MFMA(acc[4], a1, B0);
            MFMA(acc[1], a0, B1); MFMA(acc[5], a1, B1);
            MFMA(acc[3], a0, B2); MFMA(acc[7], a1, B2);
            if (t < 3) { A00 = N00; A01 = N01; A10 = N10; A11 = N11; B0 = Nb0; B1 = Nb1; B2 = Nb2; }
        }
    }
    // ---- tail step 52: sent(3)+bias-one+zeros for rza,rzb,in,hn ----
    {
        float4 A00, A01, A10, A11;
        heads_A(52, rA0, rA1, sl0, sl1, kg, h_t, h_ctx, memory, sent, A00, A01, A10, A11);
        bf16x8 a0 = cvt8(A00, A01), a1 = cvt8(A10, A11);
        bf16x8 B0 = ldB(W2f, RZa, 52, lane), B1 = ldB(W2f, RZb, 52, lane);
        bf16x8 B2 = ldB(W2f, INf, 52, lane), B3 = ldB(W2f, HNf, 52, lane);
        MFMA(acc[0], a0, B0); MFMA(acc[4], a1, B0);
        MFMA(acc[1], a0, B1); MFMA(acc[5], a1, B1);
        MFMA(acc[2], a0, B2); MFMA(acc[6], a1, B2);
        MFMA(acc[3], a0, B3); MFMA(acc[7], a1, B3);
    }
    // ---- heads K-slice: steps HS0..HS1 ----
    {
        f32x4 z = {0.f, 0.f, 0.f, 0.f};
        hacc[0] = z; hacc[1] = z;
        float4 A00, A01, A10, A11;
        heads_A(HS0, rA0, rA1, sl0, sl1, kg, h_t, h_ctx, memory, sent, A00, A01, A10, A11);
        bf16x8 Bh = ldB(W2f, 32, HS0, lane);
#pragma unroll
        for (int s = HS0; s < HS1; ++s) {
            float4 N00, N01, N10, N11; bf16x8 Nb;
            if (s < HS1 - 1) {
                heads_A(s + 1, rA0, rA1, sl0, sl1, kg, h_t, h_ctx, memory, sent, N00, N01, N10, N11);
                Nb = ldB(W2f, 32, s + 1, lane);
            }
            MFMA(hacc[0], cvt8(A00, A01), Bh);
            MFMA(hacc[1], cvt8(A10, A11), Bh);
            if (s < HS1 - 1) { A00 = N00; A01 = N01; A10 = N10; A11 = N11; Bh = Nb; }
        }
    }
}

// ---------------- dump one rowgroup's partials to LDS (RG compile-time: rule #20) ----------------
template<int W, int RG>
static __device__ __forceinline__ void dump_rg(const f32x4* __restrict__ acc,
                                               const f32x4* __restrict__ hacc, int lane,
                                               f32x4* __restrict__ red, f32x4* __restrict__ redh)
{
    red[(2 * W) * 64 + lane]     = acc[RG * 4 + 0];
    red[(2 * W + 1) * 64 + lane] = acc[RG * 4 + 1];
    red[(16 + W) * 64 + lane]    = acc[RG * 4 + 2];
    red[(24 + W) * 64 + lane]    = acc[RG * 4 + 3];
    redh[W * 64 + lane]          = hacc[RG];
}

#define DISPATCH_COMPUTE() do { switch (wave) {                                                            \
        case 0: wave_compute<0>(h_t, h_ctx, sent, memory, slot_ids, row0, lane, W2f, acc, hacc); break;    \
        case 1: wave_compute<1>(h_t, h_ctx, sent, memory, slot_ids, row0, lane, W2f, acc, hacc); break;    \
        case 2: wave_compute<2>(h_t, h_ctx, sent, memory, slot_ids, row0, lane, W2f, acc, hacc); break;    \
        case 3: wave_compute<3>(h_t, h_ctx, sent, memory, slot_ids, row0, lane, W2f, acc, hacc); break;    \
        case 4: wave_compute<4>(h_t, h_ctx, sent, memory, slot_ids, row0, lane, W2f, acc, hacc); break;    \
        case 5: wave_compute<5>(h_t, h_ctx, sent, memory, slot_ids, row0, lane, W2f, acc, hacc); break;    \
        case 6: wave_compute<6>(h_t, h_ctx, sent, memory, slot_ids, row0, lane, W2f, acc, hacc); break;    \
        default: wave_compute<7>(h_t, h_ctx, sent, memory, slot_ids, row0, lane, W2f, acc, hacc); break;   \
    } } while (0)

#define DISPATCH_DUMP(RG) do { switch (wave) {                                   \
        case 0: dump_rg<0, RG>(acc, hacc, lane, red, redh); break;               \
        case 1: dump_rg<1, RG>(acc, hacc, lane, red, redh); break;               \
        case 2: dump_rg<2, RG>(acc, hacc, lane, red, redh); break;               \
        case 3: dump_rg<3, RG>(acc, hacc, lane, red, redh); break;               \
        case 4: dump_rg<4, RG>(acc, hacc, lane, red, redh); break;               \
        case 5: dump_rg<5, RG>(acc, hacc, lane, red, redh); break;               \
        case 6: dump_rg<6, RG>(acc, hacc, lane, red, redh); break;               \
        default: dump_rg<7, RG>(acc, hacc, lane, red, redh); break;              \
    } } while (0)

// ---------------- fused GEMM (8-wave balanced N/K-split, M=32) + shared epilogue ----------------
__global__ __launch_bounds__(512, 4) void fused_kernel(
    const float* __restrict__ h_t,   const float* __restrict__ h_ctx,
    const float* __restrict__ sent,  const int* __restrict__ slot_ids,
    const float* __restrict__ memory,const ushort* __restrict__ W2f,
    const int* __restrict__ winner,
    float* __restrict__ out_emo, float* __restrict__ out_shift, float* __restrict__ out_mem)
{
    // 32 KB (frags 0..31) + 24 KB heads/pad buffer = 56 KB total.
    // 56 KB caps residency at 2 blocks/CU -> compiler's occupancy target becomes
    // 4 waves/EU -> 128-VGPR budget (round-7's 64-VGPR squeeze came from a
    // 33.8 KB / 4-block target). Only the first 8 KB of redh is used.
    __shared__ alignas(16) f32x4 red[32 * 64];
    __shared__ alignas(16) f32x4 redh[8 * 64 * 3];

    const int tid  = threadIdx.x;
    const int wave = tid >> 6;
    const int lane = tid & 63;
    const int row0 = blockIdx.x * 32;

    f32x4 acc[8], hacc[2];
    DISPATCH_COMPUTE();

    // ---- rowgroup 0: dump -> epilogue rows [row0, row0+16) ----
    DISPATCH_DUMP(0);
    __syncthreads();

#define EPILOGUE(P) do {                                                                \
        if (tid < 256) {                                                                \
            const int erow = tid >> 4, ecol = tid & 15;                                 \
            const int grow = row0 + (P) * 16 + erow;                                    \
            const int li   = (erow >> 2) * 16 + ecol;                                   \
            const int rsel = erow & 3;                                                  \
            const int slot = slot_ids[grow];                                            \
            const bool win = (winner[slot] == grow);                                    \
            _Pragma("unroll")                                                           \
            for (int q = 0; q < 8; ++q) {                                               \
                float rg  = red[q * 64 + li][rsel];                                     \
                float zg  = red[(8 + q) * 64 + li][rsel];                               \
                float inn = red[(16 + q) * 64 + li][rsel];                              \
                float hnn = red[(24 + q) * 64 + li][rsel];                              \
                rg = 1.0f / (1.0f + __expf(-rg));                                       \
                zg = 1.0f / (1.0f + __expf(-zg));                                       \
                float nn = tanhf(inn + rg * hnn);                                       \
                float h  = memory[(size_t)slot * H_SZ + q * 16 + ecol];                 \
                float sn = (1.0f - zg) * nn + zg * h;                                   \
                if (win) out_mem[(size_t)slot * H_SZ + q * 16 + ecol] = sn;             \
            }                                                                           \
            float hv = 0.0f;                                                            \
            _Pragma("unroll")                                                           \
            for (int w = 0; w < 8; ++w) hv += redh[w * 64 + li][rsel];                  \
            if (ecol < E_SZ)       out_emo[(size_t)grow * E_SZ + ecol] = hv;            \
            else if (ecol == E_SZ) out_shift[grow] = hv;                                \
        }                                                                               \
    } while (0)

    EPILOGUE(0);
    __syncthreads();

    // ---- rowgroup 1: dump -> epilogue rows [row0+16, row0+32) ----
    DISPATCH_DUMP(1);
    __syncthreads();

    EPILOGUE(1);
#undef EPILOGUE
}

// ---------------- launch ----------------
extern "C" void kernel_launch(void* const* d_in, const int* in_sizes, int n_in,
                              void* d_out, int out_size, void* d_ws, size_t ws_size,
                              hipStream_t stream)
{
    const float* h_t     = (const float*)d_in[0];
    const float* h_ctx   = (const float*)d_in[1];
    const float* sent    = (const float*)d_in[2];
    const int*   slot_ids= (const int*)  d_in[3];
    const float* memory  = (const float*)d_in[4];
    const float* W_ih    = (const float*)d_in[5];
    const float* W_hh    = (const float*)d_in[6];
    const float* b_ih    = (const float*)d_in[7];
    const float* b_hh    = (const float*)d_in[8];
    const float* W_e     = (const float*)d_in[9];
    const float* b_e     = (const float*)d_in[10];
    const float* W_s     = (const float*)d_in[11];
    const float* b_s     = (const float*)d_in[12];

    float* out       = (float*)d_out;
    float* out_emo   = out;                                    // [B,7]
    float* out_shift = out + (size_t)B_SZ * E_SZ;              // [B]
    float* out_mem   = out + (size_t)B_SZ * E_SZ + B_SZ;       // [S,H]

    int*    winner = (int*)d_ws;                               // S ints
    ushort* W2f    = (ushort*)((char*)d_ws + (size_t)S_SZ * sizeof(int));

    hipMemsetAsync(winner, 0xFF, (size_t)S_SZ * sizeof(int), stream);   // -1
    hipMemcpyAsync(out_mem, memory, (size_t)S_SZ * H_SZ * sizeof(float),
                   hipMemcpyDeviceToDevice, stream);

    pack_w2f_kernel<<<(NFR * NSTEP * 64 + 255) / 256, 256, 0, stream>>>(
        W_ih, W_hh, b_ih, b_hh, W_e, b_e, W_s, b_s, W2f);
    winner_kernel<<<B_SZ / 256, 256, 0, stream>>>(slot_ids, winner);
    fused_kernel<<<B_SZ / 32, 512, 0, stream>>>(
        h_t, h_ctx, sent, slot_ids, memory, W2f, winner, out_emo, out_shift, out_mem);
}

// Round 9
// 120.140 us; speedup vs baseline: 1.0051x; 1.0035x over previous
//
#include <hip/hip_runtime.h>
#include <hip/hip_bf16.h>

// Problem constants
#define B_SZ   16384
#define D_SZ   768
#define H_SZ   128
#define S_SZ   65536
#define E_SZ   7

// Packed GEMM geometry (logical K/N spaces; B stored frag-major, see pack kernel)
// K layout: [0,768) h_t | [768,896) s_t | [896,1664) h_ctx | 1664..1666 sent | 1667 bias(1.0) | pad->1696
// N layout: [0,256) r,z (gi+gh summed) | [256,384) i_n | [384,512) h_n | [512,519) W_e | 519 W_s | pad->528
// Frag K-activity: [0,16) rz: steps 0-27+52 | [16,24) i_n: 0-23+52 | [24,32) h_n: 24-27+52 | 32 heads: all 53
// Wave w (of 4): rz {4w..4w+3}, i_n {16+2w,17+2w}, h_n {24+2w,25+2w}, heads K-slice HSL[w]..HSL[w+1]
//   units: 4*29 + 2*25 + 2*5 + ~13 = 189-190 per wave (balanced)
#define NFR    33      // N fragments of 16
#define NSTEP  53      // K steps of 32: 24 (h_t) + 4 (s_t) + 24 (h_ctx) + 1 (tail)

typedef __attribute__((ext_vector_type(8))) short bf16x8;
typedef __attribute__((ext_vector_type(4))) float f32x4;

#define LD4(p) (*reinterpret_cast<const float4*>(p))
#define MFMA(d, a, b) d = __builtin_amdgcn_mfma_f32_16x16x32_bf16(a, b, d, 0, 0, 0)

static __device__ __forceinline__ ushort f2bf(float v) {
    unsigned u = __float_as_uint(v);
    u = (u + 0x7FFFu + ((u >> 16) & 1u)) >> 16;   // RNE (pack kernel only)
    return (ushort)u;
}

// pack two floats -> two bf16 (round-half-up) in one u32 via v_perm
static __device__ __forceinline__ unsigned pk2(float x, float y) {
    unsigned a = __float_as_uint(x) + 0x8000u;
    unsigned b = __float_as_uint(y) + 0x8000u;
    return __builtin_amdgcn_perm(b, a, 0x07060302);   // [a.hi16 | b.hi16]
}

static __device__ __forceinline__ bf16x8 cvt8(float4 a, float4 b) {
    union { unsigned u[4]; bf16x8 v; } r;
    r.u[0] = pk2(a.x, a.y); r.u[1] = pk2(a.z, a.w);
    r.u[2] = pk2(b.x, b.y); r.u[3] = pk2(b.z, b.w);
    return r.v;
}

// logical packed-weight value at (n, k)
static __device__ __forceinline__ float w2_value(int n, int k,
    const float* __restrict__ W_ih, const float* __restrict__ W_hh,
    const float* __restrict__ b_ih, const float* __restrict__ b_hh,
    const float* __restrict__ W_e,  const float* __restrict__ b_e,
    const float* __restrict__ W_s,  const float* __restrict__ b_s)
{
    float v = 0.0f;
    if (n < 256) {                       // r,z rows: gi + gh summed
        if (k < 768)                        v = W_ih[(size_t)n * 771 + k];
        else if (k < 896)                   v = W_hh[(size_t)n * 128 + (k - 768)];
        else if (k >= 1664 && k < 1667)     v = W_ih[(size_t)n * 771 + 768 + (k - 1664)];
        else if (k == 1667)                 v = b_ih[n] + b_hh[n];
    } else if (n < 384) {                // i_n rows (W_ih rows 256..383)
        if (k < 768)                        v = W_ih[(size_t)n * 771 + k];
        else if (k >= 1664 && k < 1667)     v = W_ih[(size_t)n * 771 + 768 + (k - 1664)];
        else if (k == 1667)                 v = b_ih[n];
    } else if (n < 512) {                // h_n rows (W_hh rows 256..383)
        int g = n - 128;
        if (k >= 768 && k < 896)            v = W_hh[(size_t)g * 128 + (k - 768)];
        else if (k == 1667)                 v = b_hh[g];
    } else if (n < 520) {                // heads: z_t = [h_t(0:768) sent(768:771) s_t(771:899) h_ctx(899:1667)]
        int e = n - 512;
        const float* Wr = (e < E_SZ) ? (W_e + (size_t)e * 1667) : W_s;
        if (k < 768)                        v = Wr[k];
        else if (k < 896)                   v = Wr[771 + (k - 768)];
        else if (k < 1664)                  v = Wr[899 + (k - 896)];
        else if (k < 1667)                  v = Wr[768 + (k - 1664)];
        else if (k == 1667)                 v = (e < E_SZ) ? b_e[e] : b_s[0];
    }
    return v;
}

// ---------------- pack W2 frag-major: W2f[(nf*NSTEP + kstep)*64 + lane][8] ----------------
__global__ __launch_bounds__(256) void pack_w2f_kernel(
    const float* __restrict__ W_ih, const float* __restrict__ W_hh,
    const float* __restrict__ b_ih, const float* __restrict__ b_hh,
    const float* __restrict__ W_e,  const float* __restrict__ b_e,
    const float* __restrict__ W_s,  const float* __restrict__ b_s,
    ushort* __restrict__ W2f)
{
    int tid = blockIdx.x * 256 + threadIdx.x;
    if (tid >= NFR * NSTEP * 64) return;
    int lane  = tid & 63;
    int kstep = (tid >> 6) % NSTEP;
    int nf    = tid / (NSTEP * 64);
    int n     = nf * 16 + (lane & 15);
    int kbase = kstep * 32 + (lane >> 4) * 8;
    ushort o[8];
#pragma unroll
    for (int j = 0; j < 8; ++j)
        o[j] = f2bf(w2_value(n, kbase + j, W_ih, W_hh, b_ih, b_hh, W_e, b_e, W_s, b_s));
    *reinterpret_cast<uint4*>(W2f + (size_t)tid * 8) = *reinterpret_cast<const uint4*>(o);
}

// ---------------- winner (last-write-wins) ----------------
__global__ __launch_bounds__(256) void winner_kernel(const int* __restrict__ slot_ids,
                                                     int* __restrict__ winner)
{
    int b = blockIdx.x * 256 + threadIdx.x;
    if (b < B_SZ) atomicMax(&winner[slot_ids[b]], b);
}

static __device__ __forceinline__ bf16x8 ldB(const ushort* __restrict__ W2f, int nf, int ks, int lane) {
    return *reinterpret_cast<const bf16x8*>(W2f + ((size_t)(nf * NSTEP + ks) * 64 + lane) * 8);
}

// heads A-source select; branches fold at compile time under full unroll
static __device__ __forceinline__ void heads_A(
    int s, int rA0, int rA1, int sl0, int sl1, int kg,
    const float* __restrict__ h_t, const float* __restrict__ h_ctx,
    const float* __restrict__ memory, const float* __restrict__ sent,
    float4& a00, float4& a01, float4& a10, float4& a11)
{
    if (s < 24) {
        const float* p0 = h_t + (size_t)rA0 * D_SZ + s * 32 + kg * 8;
        const float* p1 = h_t + (size_t)rA1 * D_SZ + s * 32 + kg * 8;
        a00 = LD4(p0); a01 = LD4(p0 + 4); a10 = LD4(p1); a11 = LD4(p1 + 4);
    } else if (s < 28) {
        const float* p0 = memory + (size_t)sl0 * H_SZ + (s - 24) * 32 + kg * 8;
        const float* p1 = memory + (size_t)sl1 * H_SZ + (s - 24) * 32 + kg * 8;
        a00 = LD4(p0); a01 = LD4(p0 + 4); a10 = LD4(p1); a11 = LD4(p1 + 4);
    } else if (s < 52) {
        const float* p0 = h_ctx + (size_t)rA0 * D_SZ + (s - 28) * 32 + kg * 8;
        const float* p1 = h_ctx + (size_t)rA1 * D_SZ + (s - 28) * 32 + kg * 8;
        a00 = LD4(p0); a01 = LD4(p0 + 4); a10 = LD4(p1); a11 = LD4(p1 + 4);
    } else {
        float4 z = {0.f, 0.f, 0.f, 0.f};
        a00 = z; a01 = z; a10 = z; a11 = z;
        if (kg == 0) {
            a00.x = sent[(size_t)rA0 * 3]; a00.y = sent[(size_t)rA0 * 3 + 1];
            a00.z = sent[(size_t)rA0 * 3 + 2]; a00.w = 1.0f;
            a10.x = sent[(size_t)rA1 * 3]; a10.y = sent[(size_t)rA1 * 3 + 1];
            a10.z = sent[(size_t)rA1 * 3 + 2]; a10.w = 1.0f;
        }
    }
}

// ---------------- per-wave compute: 4 rz + 2 i_n + 2 h_n frags + heads K-slice, M=32 ----------------
// acc[rg*8 + {0..3 rz, 4..5 in, 6..7 hn}], hacc[rg] = heads partial
template<int W>
static __device__ __forceinline__ void wave_compute(
    const float* __restrict__ h_t, const float* __restrict__ h_ctx,
    const float* __restrict__ sent, const float* __restrict__ memory,
    const int* __restrict__ slot_ids, int row0, int lane,
    const ushort* __restrict__ W2f, f32x4* __restrict__ acc, f32x4* __restrict__ hacc)
{
    constexpr int RZ = 4 * W;          // rz frags RZ..RZ+3
    constexpr int IN = 16 + 2 * W;     // i_n frags IN..IN+1
    constexpr int HN = 24 + 2 * W;     // h_n frags HN..HN+1
    constexpr int HSL[5] = {0, 13, 26, 39, 53};
    constexpr int HS0 = HSL[W], HS1 = HSL[W + 1];

    const int col = lane & 15, kg = lane >> 4;
    const int rA0 = row0 + col, rA1 = rA0 + 16;
    const int sl0 = slot_ids[rA0], sl1 = slot_ids[rA1];

    {
        f32x4 z = {0.f, 0.f, 0.f, 0.f};
#pragma unroll
        for (int i = 0; i < 16; ++i) acc[i] = z;
        hacc[0] = z; hacc[1] = z;
    }

#define SIX_MFMAS(F4, F5) do {                                                  \
        bf16x8 a0 = cvt8(A00, A01), a1 = cvt8(A10, A11);                        \
        MFMA(acc[0], a0, B0); MFMA(acc[8],  a1, B0);                            \
        MFMA(acc[1], a0, B1); MFMA(acc[9],  a1, B1);                            \
        MFMA(acc[2], a0, B2); MFMA(acc[10], a1, B2);                            \
        MFMA(acc[3], a0, B3); MFMA(acc[11], a1, B3);                            \
        MFMA(acc[F4], a0, B4); MFMA(acc[8 + F4], a1, B4);                       \
        MFMA(acc[F5], a0, B5); MFMA(acc[8 + F5], a1, B5);                       \
    } while (0)

    // ---- h_t phase: steps 0..23, frags rz x4 + i_n x2 (2-deep pipeline) ----
    {
        const float* p0 = h_t + (size_t)rA0 * D_SZ + kg * 8;
        const float* p1 = h_t + (size_t)rA1 * D_SZ + kg * 8;
        float4 A00 = LD4(p0), A01 = LD4(p0 + 4), A10 = LD4(p1), A11 = LD4(p1 + 4);
        bf16x8 B0 = ldB(W2f, RZ, 0, lane),     B1 = ldB(W2f, RZ + 1, 0, lane);
        bf16x8 B2 = ldB(W2f, RZ + 2, 0, lane), B3 = ldB(W2f, RZ + 3, 0, lane);
        bf16x8 B4 = ldB(W2f, IN, 0, lane),     B5 = ldB(W2f, IN + 1, 0, lane);
#pragma unroll
        for (int s = 0; s < 24; ++s) {
            float4 N00, N01, N10, N11; bf16x8 Nb0, Nb1, Nb2, Nb3, Nb4, Nb5;
            if (s < 23) {
                N00 = LD4(p0 + (s + 1) * 32); N01 = LD4(p0 + (s + 1) * 32 + 4);
                N10 = LD4(p1 + (s + 1) * 32); N11 = LD4(p1 + (s + 1) * 32 + 4);
                Nb0 = ldB(W2f, RZ, s + 1, lane);     Nb1 = ldB(W2f, RZ + 1, s + 1, lane);
                Nb2 = ldB(W2f, RZ + 2, s + 1, lane); Nb3 = ldB(W2f, RZ + 3, s + 1, lane);
                Nb4 = ldB(W2f, IN, s + 1, lane);     Nb5 = ldB(W2f, IN + 1, s + 1, lane);
            }
            SIX_MFMAS(4, 5);
            if (s < 23) {
                A00 = N00; A01 = N01; A10 = N10; A11 = N11;
                B0 = Nb0; B1 = Nb1; B2 = Nb2; B3 = Nb3; B4 = Nb4; B5 = Nb5;
            }
        }
    }
    // ---- s_t phase: steps 24..27, frags rz x4 + h_n x2 (gather) ----
    {
        const float* p0 = memory + (size_t)sl0 * H_SZ + kg * 8;
        const float* p1 = memory + (size_t)sl1 * H_SZ + kg * 8;
        float4 A00 = LD4(p0), A01 = LD4(p0 + 4), A10 = LD4(p1), A11 = LD4(p1 + 4);
        bf16x8 B0 = ldB(W2f, RZ, 24, lane),     B1 = ldB(W2f, RZ + 1, 24, lane);
        bf16x8 B2 = ldB(W2f, RZ + 2, 24, lane), B3 = ldB(W2f, RZ + 3, 24, lane);
        bf16x8 B4 = ldB(W2f, HN, 24, lane),     B5 = ldB(W2f, HN + 1, 24, lane);
#pragma unroll
        for (int t = 0; t < 4; ++t) {
            float4 N00, N01, N10, N11; bf16x8 Nb0, Nb1, Nb2, Nb3, Nb4, Nb5;
            if (t < 3) {
                N00 = LD4(p0 + (t + 1) * 32); N01 = LD4(p0 + (t + 1) * 32 + 4);
                N10 = LD4(p1 + (t + 1) * 32); N11 = LD4(p1 + (t + 1) * 32 + 4);
                Nb0 = ldB(W2f, RZ, 25 + t, lane);     Nb1 = ldB(W2f, RZ + 1, 25 + t, lane);
                Nb2 = ldB(W2f, RZ + 2, 25 + t, lane); Nb3 = ldB(W2f, RZ + 3, 25 + t, lane);
                Nb4 = ldB(W2f, HN, 25 + t, lane);     Nb5 = ldB(W2f, HN + 1, 25 + t, lane);
            }
            SIX_MFMAS(6, 7);
            if (t < 3) {
                A00 = N00; A01 = N01; A10 = N10; A11 = N11;
                B0 = Nb0; B1 = Nb1; B2 = Nb2; B3 = Nb3; B4 = Nb4; B5 = Nb5;
            }
        }
    }
    // ---- tail step 52: sent(3)+bias-one+zeros for all 8 owned non-head frags ----
    {
        float4 A00, A01, A10, A11;
        heads_A(52, rA0, rA1, sl0, sl1, kg, h_t, h_ctx, memory, sent, A00, A01, A10, A11);
        bf16x8 a0 = cvt8(A00, A01), a1 = cvt8(A10, A11);
        bf16x8 T0 = ldB(W2f, RZ, 52, lane),     T1 = ldB(W2f, RZ + 1, 52, lane);
        bf16x8 T2 = ldB(W2f, RZ + 2, 52, lane), T3 = ldB(W2f, RZ + 3, 52, lane);
        bf16x8 T4 = ldB(W2f, IN, 52, lane),     T5 = ldB(W2f, IN + 1, 52, lane);
        bf16x8 T6 = ldB(W2f, HN, 52, lane),     T7 = ldB(W2f, HN + 1, 52, lane);
        MFMA(acc[0], a0, T0); MFMA(acc[8],  a1, T0);
        MFMA(acc[1], a0, T1); MFMA(acc[9],  a1, T1);
        MFMA(acc[2], a0, T2); MFMA(acc[10], a1, T2);
        MFMA(acc[3], a0, T3); MFMA(acc[11], a1, T3);
        MFMA(acc[4], a0, T4); MFMA(acc[12], a1, T4);
        MFMA(acc[5], a0, T5); MFMA(acc[13], a1, T5);
        MFMA(acc[6], a0, T6); MFMA(acc[14], a1, T6);
        MFMA(acc[7], a0, T7); MFMA(acc[15], a1, T7);
    }
    // ---- heads K-slice: steps HS0..HS1 (2-deep pipeline) ----
    {
        float4 A00, A01, A10, A11;
        heads_A(HS0, rA0, rA1, sl0, sl1, kg, h_t, h_ctx, memory, sent, A00, A01, A10, A11);
        bf16x8 Bh = ldB(W2f, 32, HS0, lane);
#pragma unroll
        for (int s = HS0; s < HS1; ++s) {
            float4 N00, N01, N10, N11; bf16x8 Nb;
            if (s < HS1 - 1) {
                heads_A(s + 1, rA0, rA1, sl0, sl1, kg, h_t, h_ctx, memory, sent, N00, N01, N10, N11);
                Nb = ldB(W2f, 32, s + 1, lane);
            }
            MFMA(hacc[0], cvt8(A00, A01), Bh);
            MFMA(hacc[1], cvt8(A10, A11), Bh);
            if (s < HS1 - 1) { A00 = N00; A01 = N01; A10 = N10; A11 = N11; Bh = Nb; }
        }
    }
#undef SIX_MFMAS
}

// ---------------- dump one rowgroup's partials to LDS (RG compile-time: rule #20) ----------------
template<int W, int RG>
static __device__ __forceinline__ void dump_rg(const f32x4* __restrict__ acc,
                                               const f32x4* __restrict__ hacc, int lane,
                                               f32x4* __restrict__ red, f32x4* __restrict__ redh)
{
#pragma unroll
    for (int i = 0; i < 4; ++i) red[(4 * W + i) * 64 + lane]      = acc[RG * 8 + i];
#pragma unroll
    for (int i = 0; i < 2; ++i) red[(16 + 2 * W + i) * 64 + lane] = acc[RG * 8 + 4 + i];
#pragma unroll
    for (int i = 0; i < 2; ++i) red[(24 + 2 * W + i) * 64 + lane] = acc[RG * 8 + 6 + i];
    redh[W * 64 + lane] = hacc[RG];
}

#define DISPATCH_COMPUTE() do { switch (wave) {                                                            \
        case 0: wave_compute<0>(h_t, h_ctx, sent, memory, slot_ids, row0, lane, W2f, acc, hacc); break;    \
        case 1: wave_compute<1>(h_t, h_ctx, sent, memory, slot_ids, row0, lane, W2f, acc, hacc); break;    \
        case 2: wave_compute<2>(h_t, h_ctx, sent, memory, slot_ids, row0, lane, W2f, acc, hacc); break;    \
        default: wave_compute<3>(h_t, h_ctx, sent, memory, slot_ids, row0, lane, W2f, acc, hacc); break;   \
    } } while (0)

#define DISPATCH_DUMP(RG) do { switch (wave) {                                   \
        case 0: dump_rg<0, RG>(acc, hacc, lane, red, redh); break;               \
        case 1: dump_rg<1, RG>(acc, hacc, lane, red, redh); break;               \
        case 2: dump_rg<2, RG>(acc, hacc, lane, red, redh); break;               \
        default: dump_rg<3, RG>(acc, hacc, lane, red, redh); break;              \
    } } while (0)

// ---------------- fused GEMM (4-wave balanced split, M=32) + copy + shared epilogue ----------------
__global__ __launch_bounds__(256, 3) void fused_kernel(
    const float* __restrict__ h_t,   const float* __restrict__ h_ctx,
    const float* __restrict__ sent,  const int* __restrict__ slot_ids,
    const float* __restrict__ memory,const ushort* __restrict__ W2f,
    const int* __restrict__ winner,
    float* __restrict__ out_emo, float* __restrict__ out_shift, float* __restrict__ out_mem)
{
    __shared__ alignas(16) f32x4 red[32 * 64];   // 32 KB
    __shared__ alignas(16) f32x4 redh[4 * 64];   // 4 KB heads partials

    const int tid  = threadIdx.x;
    const int wave = tid >> 6;
    const int lane = tid & 63;
    const int row0 = blockIdx.x * 32;

    // ---- merged base-copy: this block owns slots [blk*128, blk*128+128).
    // Copy rows nobody scatters to (winner<0); epilogue writes winner rows.
    // Disjoint -> no ordering needed; HBM traffic drains under the GEMM.
    {
        const int sbase = blockIdx.x * 128;
#pragma unroll
        for (int it = 0; it < 16; ++it) {
            int idx  = it * 256 + tid;          // 0..4095
            int r    = idx >> 5;                // row 0..127
            int c    = (idx & 31) * 4;          // col 0..124
            int slot = sbase + r;
            if (winner[slot] < 0) {
                float4 v = LD4(memory + (size_t)slot * H_SZ + c);
                *reinterpret_cast<float4*>(out_mem + (size_t)slot * H_SZ + c) = v;
            }
        }
    }

    f32x4 acc[16], hacc[2];
    DISPATCH_COMPUTE();

    // ---- rowgroup 0: dump -> epilogue rows [row0, row0+16) ----
    DISPATCH_DUMP(0);
    __syncthreads();

#define EPILOGUE(P) do {                                                                \
        {                                                                               \
            const int erow = tid >> 4, ecol = tid & 15;                                 \
            const int grow = row0 + (P) * 16 + erow;                                    \
            const int li   = (erow >> 2) * 16 + ecol;                                   \
            const int rsel = erow & 3;                                                  \
            const int slot = slot_ids[grow];                                            \
            const bool win = (winner[slot] == grow);                                    \
            _Pragma("unroll")                                                           \
            for (int q = 0; q < 8; ++q) {                                               \
                float rg  = red[q * 64 + li][rsel];                                     \
                float zg  = red[(8 + q) * 64 + li][rsel];                               \
                float inn = red[(16 + q) * 64 + li][rsel];                              \
                float hnn = red[(24 + q) * 64 + li][rsel];                              \
                rg = 1.0f / (1.0f + __expf(-rg));                                       \
                zg = 1.0f / (1.0f + __expf(-zg));                                       \
                float nn = tanhf(inn + rg * hnn);                                       \
                float h  = memory[(size_t)slot * H_SZ + q * 16 + ecol];                 \
                float sn = (1.0f - zg) * nn + zg * h;                                   \
                if (win) out_mem[(size_t)slot * H_SZ + q * 16 + ecol] = sn;             \
            }                                                                           \
            float hv = redh[0 * 64 + li][rsel] + redh[1 * 64 + li][rsel]                \
                     + redh[2 * 64 + li][rsel] + redh[3 * 64 + li][rsel];               \
            if (ecol < E_SZ)       out_emo[(size_t)grow * E_SZ + ecol] = hv;            \
            else if (ecol == E_SZ) out_shift[grow] = hv;                                \
        }                                                                               \
    } while (0)

    EPILOGUE(0);
    __syncthreads();

    // ---- rowgroup 1: dump -> epilogue rows [row0+16, row0+32) ----
    DISPATCH_DUMP(1);
    __syncthreads();

    EPILOGUE(1);
#undef EPILOGUE
}

// ---------------- launch ----------------
extern "C" void kernel_launch(void* const* d_in, const int* in_sizes, int n_in,
                              void* d_out, int out_size, void* d_ws, size_t ws_size,
                              hipStream_t stream)
{
    const float* h_t     = (const float*)d_in[0];
    const float* h_ctx   = (const float*)d_in[1];
    const float* sent    = (const float*)d_in[2];
    const int*   slot_ids= (const int*)  d_in[3];
    const float* memory  = (const float*)d_in[4];
    const float* W_ih    = (const float*)d_in[5];
    const float* W_hh    = (const float*)d_in[6];
    const float* b_ih    = (const float*)d_in[7];
    const float* b_hh    = (const float*)d_in[8];
    const float* W_e     = (const float*)d_in[9];
    const float* b_e     = (const float*)d_in[10];
    const float* W_s     = (const float*)d_in[11];
    const float* b_s     = (const float*)d_in[12];

    float* out       = (float*)d_out;
    float* out_emo   = out;                                    // [B,7]
    float* out_shift = out + (size_t)B_SZ * E_SZ;              // [B]
    float* out_mem   = out + (size_t)B_SZ * E_SZ + B_SZ;       // [S,H]

    int*    winner = (int*)d_ws;                               // S ints
    ushort* W2f    = (ushort*)((char*)d_ws + (size_t)S_SZ * sizeof(int));

    hipMemsetAsync(winner, 0xFF, (size_t)S_SZ * sizeof(int), stream);   // -1

    pack_w2f_kernel<<<(NFR * NSTEP * 64 + 255) / 256, 256, 0, stream>>>(
        W_ih, W_hh, b_ih, b_hh, W_e, b_e, W_s, b_s, W2f);
    winner_kernel<<<B_SZ / 256, 256, 0, stream>>>(slot_ids, winner);
    fused_kernel<<<B_SZ / 32, 256, 0, stream>>>(
        h_t, h_ctx, sent, slot_ids, memory, W2f, winner, out_emo, out_shift, out_mem);
}

// Round 10
// 99.961 us; speedup vs baseline: 1.2080x; 1.2019x over previous
//
#include <hip/hip_runtime.h>
#include <hip/hip_bf16.h>

// Problem constants
#define B_SZ   16384
#define D_SZ   768
#define H_SZ   128
#define S_SZ   65536
#define E_SZ   7

// Packed GEMM geometry (logical K/N spaces; B stored frag-major, see pack kernel)
// K layout: [0,768) h_t | [768,896) s_t | [896,1664) h_ctx | 1664..1666 sent | 1667 bias(1.0) | pad->1696
// N layout: [0,256) r,z (gi+gh summed) | [256,384) i_n | [384,512) h_n | [512,519) W_e | 519 W_s | pad->528
// K chunks: 13 chunks x 4 steps (steps of 32 floats): 0-5 h_t, 6 s_t, 7-12 h_ctx; step 52 (tail) in registers.
// Wave w (of 4): rz {4w..4w+3}, i_n {16+2w,17+2w}, h_n {24+2w,25+2w}; heads at local step st==w of every chunk.
#define NFR    33
#define NSTEP  53

typedef __attribute__((ext_vector_type(8))) short bf16x8;
typedef __attribute__((ext_vector_type(4))) float f32x4;

#define LD4(p) (*reinterpret_cast<const float4*>(p))
#define MFMA(d, a, b) d = __builtin_amdgcn_mfma_f32_16x16x32_bf16(a, b, d, 0, 0, 0)

// async global->LDS DMA, 16B per lane, dest = wave-uniform base + lane*16
#define GLDS(gp, lp) __builtin_amdgcn_global_load_lds(                              \
        (const __attribute__((address_space(1))) unsigned int*)(gp),                \
        (__attribute__((address_space(3))) unsigned int*)(lp), 16, 0, 0)

static __device__ __forceinline__ ushort f2bf(float v) {
    unsigned u = __float_as_uint(v);
    u = (u + 0x7FFFu + ((u >> 16) & 1u)) >> 16;   // RNE (pack kernel / tail only)
    return (ushort)u;
}

static __device__ __forceinline__ unsigned pk2(float x, float y) {
    unsigned a = __float_as_uint(x) + 0x8000u;
    unsigned b = __float_as_uint(y) + 0x8000u;
    return __builtin_amdgcn_perm(b, a, 0x07060302);   // [a.hi16 | b.hi16]
}

static __device__ __forceinline__ bf16x8 cvt8(float4 a, float4 b) {
    union { unsigned u[4]; bf16x8 v; } r;
    r.u[0] = pk2(a.x, a.y); r.u[1] = pk2(a.z, a.w);
    r.u[2] = pk2(b.x, b.y); r.u[3] = pk2(b.z, b.w);
    return r.v;
}

// logical packed-weight value at (n, k)
static __device__ __forceinline__ float w2_value(int n, int k,
    const float* __restrict__ W_ih, const float* __restrict__ W_hh,
    const float* __restrict__ b_ih, const float* __restrict__ b_hh,
    const float* __restrict__ W_e,  const float* __restrict__ b_e,
    const float* __restrict__ W_s,  const float* __restrict__ b_s)
{
    float v = 0.0f;
    if (n < 256) {
        if (k < 768)                        v = W_ih[(size_t)n * 771 + k];
        else if (k < 896)                   v = W_hh[(size_t)n * 128 + (k - 768)];
        else if (k >= 1664 && k < 1667)     v = W_ih[(size_t)n * 771 + 768 + (k - 1664)];
        else if (k == 1667)                 v = b_ih[n] + b_hh[n];
    } else if (n < 384) {
        if (k < 768)                        v = W_ih[(size_t)n * 771 + k];
        else if (k >= 1664 && k < 1667)     v = W_ih[(size_t)n * 771 + 768 + (k - 1664)];
        else if (k == 1667)                 v = b_ih[n];
    } else if (n < 512) {
        int g = n - 128;
        if (k >= 768 && k < 896)            v = W_hh[(size_t)g * 128 + (k - 768)];
        else if (k == 1667)                 v = b_hh[g];
    } else if (n < 520) {
        int e = n - 512;
        const float* Wr = (e < E_SZ) ? (W_e + (size_t)e * 1667) : W_s;
        if (k < 768)                        v = Wr[k];
        else if (k < 896)                   v = Wr[771 + (k - 768)];
        else if (k < 1664)                  v = Wr[899 + (k - 896)];
        else if (k < 1667)                  v = Wr[768 + (k - 1664)];
        else if (k == 1667)                 v = (e < E_SZ) ? b_e[e] : b_s[0];
    }
    return v;
}

// ---------------- pack W2 frag-major: W2f[(nf*NSTEP + kstep)*64 + lane][8] ----------------
__global__ __launch_bounds__(256) void pack_w2f_kernel(
    const float* __restrict__ W_ih, const float* __restrict__ W_hh,
    const float* __restrict__ b_ih, const float* __restrict__ b_hh,
    const float* __restrict__ W_e,  const float* __restrict__ b_e,
    const float* __restrict__ W_s,  const float* __restrict__ b_s,
    ushort* __restrict__ W2f)
{
    int tid = blockIdx.x * 256 + threadIdx.x;
    if (tid >= NFR * NSTEP * 64) return;
    int lane  = tid & 63;
    int kstep = (tid >> 6) % NSTEP;
    int nf    = tid / (NSTEP * 64);
    int n     = nf * 16 + (lane & 15);
    int kbase = kstep * 32 + (lane >> 4) * 8;
    ushort o[8];
#pragma unroll
    for (int j = 0; j < 8; ++j)
        o[j] = f2bf(w2_value(n, kbase + j, W_ih, W_hh, b_ih, b_hh, W_e, b_e, W_s, b_s));
    *reinterpret_cast<uint4*>(W2f + (size_t)tid * 8) = *reinterpret_cast<const uint4*>(o);
}

// ---------------- winner (last-write-wins) ----------------
__global__ __launch_bounds__(256) void winner_kernel(const int* __restrict__ slot_ids,
                                                     int* __restrict__ winner)
{
    int b = blockIdx.x * 256 + threadIdx.x;
    if (b < B_SZ) atomicMax(&winner[slot_ids[b]], b);
}

static __device__ __forceinline__ bf16x8 ldB(const ushort* __restrict__ W2f, int nf, int ks, int lane) {
    return *reinterpret_cast<const bf16x8*>(W2f + ((size_t)(nf * NSTEP + ks) * 64 + lane) * 8);
}

// LDS A read: step st, row, 16B-chunk h (0..7); XOR-swizzled (matches pre-swizzled DMA source)
static __device__ __forceinline__ float4 lds_rd(const char* A_buf, int st, int row, int h) {
    return *reinterpret_cast<const float4*>(A_buf + st * 4096 + row * 128 + ((h ^ (row & 7)) << 4));
}

// ---------------- per-chunk compute. KIND: 0=h_t (rz+i_n), 1=s_t (rz+h_n), 2=h_ctx (heads only) ----------------
// acc[rg*8 + {0..3 rz, 4..5 in, 6..7 hn}]; heads at local step st==W into hacc.
// Also issues the NEXT chunk's A-stage DMAs AFTER the B loads (so counted vmcnt on B
// doesn't have to drain the stage).
template<int W, int KIND>
static __device__ __forceinline__ void compute_chunk(
    int c, const char* A_buf, int lane, const ushort* __restrict__ W2f,
    f32x4* __restrict__ acc, f32x4* __restrict__ hacc,
    bool do_stage, char* A_nxt, int wave,
    const float* __restrict__ h_t, const float* __restrict__ h_ctx,
    const float* __restrict__ memory, int row0, int srow, int scg, int sslot)
{
    const int cl = lane & 15, kg = lane >> 4;
    const int r0 = cl, r1 = 16 + cl;

    if constexpr (KIND == 2) {
        bf16x8 Bh = ldB(W2f, 32, c * 4 + W, lane);
        if (do_stage) {
#pragma unroll
            for (int st = 0; st < 4; ++st) {
                int s = (c + 1) * 4 + st;
                const float* g = (s < 52) ? h_ctx + (size_t)(row0 + srow) * D_SZ + (s - 28) * 32 + scg * 4
                                          : h_ctx; // unreachable (c<12 => s<52)
                GLDS(g, A_nxt + st * 4096 + wave * 1024);
            }
        }
        float4 x0 = lds_rd(A_buf, W, r0, 2 * kg), x1 = lds_rd(A_buf, W, r0, 2 * kg + 1);
        float4 y0 = lds_rd(A_buf, W, r1, 2 * kg), y1 = lds_rd(A_buf, W, r1, 2 * kg + 1);
        MFMA(hacc[0], cvt8(x0, x1), Bh);
        MFMA(hacc[1], cvt8(y0, y1), Bh);
    } else {
        constexpr int RZ = 4 * W;
        constexpr int F5 = (KIND == 0) ? (16 + 2 * W) : (24 + 2 * W);
        constexpr int A5 = (KIND == 0) ? 4 : 6;       // acc slot of 5th/6th frags
        bf16x8 Bf[6][4];
#pragma unroll
        for (int st = 0; st < 4; ++st) {
            Bf[0][st] = ldB(W2f, RZ + 0, c * 4 + st, lane);
            Bf[1][st] = ldB(W2f, RZ + 1, c * 4 + st, lane);
            Bf[2][st] = ldB(W2f, RZ + 2, c * 4 + st, lane);
            Bf[3][st] = ldB(W2f, RZ + 3, c * 4 + st, lane);
            Bf[4][st] = ldB(W2f, F5 + 0, c * 4 + st, lane);
            Bf[5][st] = ldB(W2f, F5 + 1, c * 4 + st, lane);
        }
        bf16x8 Bh = ldB(W2f, 32, c * 4 + W, lane);
        if (do_stage) {
#pragma unroll
            for (int st = 0; st < 4; ++st) {
                int s = (c + 1) * 4 + st;
                const float* g;
                if (s < 24)      g = h_t    + (size_t)(row0 + srow) * D_SZ + s * 32 + scg * 4;
                else if (s < 28) g = memory + (size_t)sslot * H_SZ + (s - 24) * 32 + scg * 4;
                else             g = h_ctx  + (size_t)(row0 + srow) * D_SZ + (s - 28) * 32 + scg * 4;
                GLDS(g, A_nxt + st * 4096 + wave * 1024);
            }
        }
#pragma unroll
        for (int st = 0; st < 4; ++st) {
            float4 x0 = lds_rd(A_buf, st, r0, 2 * kg), x1 = lds_rd(A_buf, st, r0, 2 * kg + 1);
            float4 y0 = lds_rd(A_buf, st, r1, 2 * kg), y1 = lds_rd(A_buf, st, r1, 2 * kg + 1);
            bf16x8 a0 = cvt8(x0, x1), a1 = cvt8(y0, y1);
            MFMA(acc[0],      a0, Bf[0][st]); MFMA(acc[8],      a1, Bf[0][st]);
            MFMA(acc[1],      a0, Bf[1][st]); MFMA(acc[9],      a1, Bf[1][st]);
            MFMA(acc[2],      a0, Bf[2][st]); MFMA(acc[10],     a1, Bf[2][st]);
            MFMA(acc[3],      a0, Bf[3][st]); MFMA(acc[11],     a1, Bf[3][st]);
            MFMA(acc[A5],     a0, Bf[4][st]); MFMA(acc[8 + A5], a1, Bf[4][st]);
            MFMA(acc[A5 + 1], a0, Bf[5][st]); MFMA(acc[9 + A5], a1, Bf[5][st]);
            if (st == W) { MFMA(hacc[0], a0, Bh); MFMA(hacc[1], a1, Bh); }
        }
    }
}

// ---------------- tail step 52 (register A path) ----------------
template<int W>
static __device__ __forceinline__ void tail_compute(
    const float* __restrict__ sent, int row0, int lane,
    const ushort* __restrict__ W2f, f32x4* __restrict__ acc, f32x4* __restrict__ hacc)
{
    constexpr int RZ = 4 * W, IN = 16 + 2 * W, HN = 24 + 2 * W;
    const int cl = lane & 15, kg = lane >> 4;
    const int rA0 = row0 + cl, rA1 = rA0 + 16;
    bf16x8 a0, a1;
#pragma unroll
    for (int j = 0; j < 8; ++j) {
        int kk = kg * 8 + j;
        float v0 = 0.0f, v1 = 0.0f;
        if (kk < 3)       { v0 = sent[(size_t)rA0 * 3 + kk]; v1 = sent[(size_t)rA1 * 3 + kk]; }
        else if (kk == 3) { v0 = 1.0f; v1 = 1.0f; }
        a0[j] = (short)f2bf(v0); a1[j] = (short)f2bf(v1);
    }
    bf16x8 T0 = ldB(W2f, RZ, 52, lane),     T1 = ldB(W2f, RZ + 1, 52, lane);
    bf16x8 T2 = ldB(W2f, RZ + 2, 52, lane), T3 = ldB(W2f, RZ + 3, 52, lane);
    bf16x8 T4 = ldB(W2f, IN, 52, lane),     T5 = ldB(W2f, IN + 1, 52, lane);
    bf16x8 T6 = ldB(W2f, HN, 52, lane),     T7 = ldB(W2f, HN + 1, 52, lane);
    MFMA(acc[0], a0, T0); MFMA(acc[8],  a1, T0);
    MFMA(acc[1], a0, T1); MFMA(acc[9],  a1, T1);
    MFMA(acc[2], a0, T2); MFMA(acc[10], a1, T2);
    MFMA(acc[3], a0, T3); MFMA(acc[11], a1, T3);
    MFMA(acc[4], a0, T4); MFMA(acc[12], a1, T4);
    MFMA(acc[5], a0, T5); MFMA(acc[13], a1, T5);
    MFMA(acc[6], a0, T6); MFMA(acc[14], a1, T6);
    MFMA(acc[7], a0, T7); MFMA(acc[15], a1, T7);
    if constexpr (W == 0) {
        bf16x8 Bh = ldB(W2f, 32, 52, lane);
        MFMA(hacc[0], a0, Bh); MFMA(hacc[1], a1, Bh);
    }
}

// ---------------- dump one rowgroup's partials to LDS ----------------
template<int W, int RG>
static __device__ __forceinline__ void dump_rg(const f32x4* __restrict__ acc,
                                               const f32x4* __restrict__ hacc, int lane,
                                               f32x4* __restrict__ red, f32x4* __restrict__ redh)
{
#pragma unroll
    for (int i = 0; i < 4; ++i) red[(4 * W + i) * 64 + lane]      = acc[RG * 8 + i];
#pragma unroll
    for (int i = 0; i < 2; ++i) red[(16 + 2 * W + i) * 64 + lane] = acc[RG * 8 + 4 + i];
#pragma unroll
    for (int i = 0; i < 2; ++i) red[(24 + 2 * W + i) * 64 + lane] = acc[RG * 8 + 6 + i];
    redh[W * 64 + lane] = hacc[RG];
}

#define DISPATCH_CHUNK(KIND) do { switch (wave) {                                                          \
        case 0: compute_chunk<0, KIND>(c, Ab, lane, W2f, acc, hacc, ds, An, wave, h_t, h_ctx, memory, row0, srow, scg, sslot); break; \
        case 1: compute_chunk<1, KIND>(c, Ab, lane, W2f, acc, hacc, ds, An, wave, h_t, h_ctx, memory, row0, srow, scg, sslot); break; \
        case 2: compute_chunk<2, KIND>(c, Ab, lane, W2f, acc, hacc, ds, An, wave, h_t, h_ctx, memory, row0, srow, scg, sslot); break; \
        default: compute_chunk<3, KIND>(c, Ab, lane, W2f, acc, hacc, ds, An, wave, h_t, h_ctx, memory, row0, srow, scg, sslot); break; \
    } } while (0)

#define DISPATCH_DUMP(RG) do { switch (wave) {                                   \
        case 0: dump_rg<0, RG>(acc, hacc, lane, red, redh); break;               \
        case 1: dump_rg<1, RG>(acc, hacc, lane, red, redh); break;               \
        case 2: dump_rg<2, RG>(acc, hacc, lane, red, redh); break;               \
        default: dump_rg<3, RG>(acc, hacc, lane, red, redh); break;              \
    } } while (0)

// ---------------- fused GEMM (LDS-staged A via global_load_lds) + copy + epilogue ----------------
__global__ __launch_bounds__(256, 2) void fused_kernel(
    const float* __restrict__ h_t,   const float* __restrict__ h_ctx,
    const float* __restrict__ sent,  const int* __restrict__ slot_ids,
    const float* __restrict__ memory,const ushort* __restrict__ W2f,
    const int* __restrict__ winner,
    float* __restrict__ out_emo, float* __restrict__ out_shift, float* __restrict__ out_mem)
{
    __shared__ alignas(16) char  A_st[2][4 * 4096];   // 32 KB: 2 bufs x 4 steps x [32 rows][128 B]
    __shared__ alignas(16) f32x4 red[32 * 64];        // 32 KB
    __shared__ alignas(16) f32x4 redh[4 * 64];        // 4 KB

    const int tid  = threadIdx.x;
    const int wave = tid >> 6;
    const int lane = tid & 63;
    const int row0 = blockIdx.x * 32;

    // staging identity: thread covers (row = tid>>3, lds-chunk = tid&7); global chunk pre-swizzled
    const int srow  = tid >> 3;
    const int scg   = (tid & 7) ^ (srow & 7);
    const int sslot = slot_ids[row0 + srow];

    f32x4 acc[16], hacc[2];
    {
        f32x4 z = {0.f, 0.f, 0.f, 0.f};
#pragma unroll
        for (int i = 0; i < 16; ++i) acc[i] = z;
        hacc[0] = z; hacc[1] = z;
    }

    // prologue: stage chunk 0 (h_t steps 0..3)
    {
#pragma unroll
        for (int st = 0; st < 4; ++st) {
            const float* g = h_t + (size_t)(row0 + srow) * D_SZ + st * 32 + scg * 4;
            GLDS(g, &A_st[0][st * 4096 + wave * 1024]);
        }
    }
    __syncthreads();   // drains prologue DMAs (compiler emits vmcnt(0) before barrier)

    for (int c = 0; c < 13; ++c) {
        const char* Ab = A_st[c & 1];
        char*       An = A_st[(c + 1) & 1];
        const bool  ds = (c < 12);
        // merged base-copy slice: rides inside this chunk's stage-drain window.
        {
            int i0 = (c < 3) ? 2 * c : c + 3;
            int n  = (c < 3) ? 2 : 1;
            for (int k = 0; k < n; ++k) {
                int idx = (i0 + k) * 256 + tid;       // 0..4095
                int r   = idx >> 5;                   // slot row 0..127
                int c4  = (idx & 31) * 4;             // col 0..124
                int slot = blockIdx.x * 128 + r;
                if (winner[slot] < 0) {
                    float4 v = LD4(memory + (size_t)slot * H_SZ + c4);
                    *reinterpret_cast<float4*>(out_mem + (size_t)slot * H_SZ + c4) = v;
                }
            }
        }
        if (c < 6)       DISPATCH_CHUNK(0);
        else if (c == 6) DISPATCH_CHUNK(1);
        else             DISPATCH_CHUNK(2);
        __syncthreads();   // drains stage(c+1) + all loads; ensures buffer swap safe
    }

    // tail step 52
    switch (wave) {
    case 0: tail_compute<0>(sent, row0, lane, W2f, acc, hacc); break;
    case 1: tail_compute<1>(sent, row0, lane, W2f, acc, hacc); break;
    case 2: tail_compute<2>(sent, row0, lane, W2f, acc, hacc); break;
    default: tail_compute<3>(sent, row0, lane, W2f, acc, hacc); break;
    }

    // ---- rowgroup 0: dump -> epilogue rows [row0, row0+16) ----
    DISPATCH_DUMP(0);
    __syncthreads();

#define EPILOGUE(P) do {                                                                \
        {                                                                               \
            const int erow = tid >> 4, ecol = tid & 15;                                 \
            const int grow = row0 + (P) * 16 + erow;                                    \
            const int li   = (erow >> 2) * 16 + ecol;                                   \
            const int rsel = erow & 3;                                                  \
            const int slot = slot_ids[grow];                                            \
            const bool win = (winner[slot] == grow);                                    \
            _Pragma("unroll")                                                           \
            for (int q = 0; q < 8; ++q) {                                               \
                float rg  = red[q * 64 + li][rsel];                                     \
                float zg  = red[(8 + q) * 64 + li][rsel];                               \
                float inn = red[(16 + q) * 64 + li][rsel];                              \
                float hnn = red[(24 + q) * 64 + li][rsel];                              \
                rg = 1.0f / (1.0f + __expf(-rg));                                       \
                zg = 1.0f / (1.0f + __expf(-zg));                                       \
                float nn = tanhf(inn + rg * hnn);                                       \
                float h  = memory[(size_t)slot * H_SZ + q * 16 + ecol];                 \
                float sn = (1.0f - zg) * nn + zg * h;                                   \
                if (win) out_mem[(size_t)slot * H_SZ + q * 16 + ecol] = sn;             \
            }                                                                           \
            float hv = redh[0 * 64 + li][rsel] + redh[1 * 64 + li][rsel]                \
                     + redh[2 * 64 + li][rsel] + redh[3 * 64 + li][rsel];               \
            if (ecol < E_SZ)       out_emo[(size_t)grow * E_SZ + ecol] = hv;            \
            else if (ecol == E_SZ) out_shift[grow] = hv;                                \
        }                                                                               \
    } while (0)

    EPILOGUE(0);
    __syncthreads();

    // ---- rowgroup 1: dump -> epilogue rows [row0+16, row0+32) ----
    DISPATCH_DUMP(1);
    __syncthreads();

    EPILOGUE(1);
#undef EPILOGUE
}

// ---------------- launch ----------------
extern "C" void kernel_launch(void* const* d_in, const int* in_sizes, int n_in,
                              void* d_out, int out_size, void* d_ws, size_t ws_size,
                              hipStream_t stream)
{
    const float* h_t     = (const float*)d_in[0];
    const float* h_ctx   = (const float*)d_in[1];
    const float* sent    = (const float*)d_in[2];
    const int*   slot_ids= (const int*)  d_in[3];
    const float* memory  = (const float*)d_in[4];
    const float* W_ih    = (const float*)d_in[5];
    const float* W_hh    = (const float*)d_in[6];
    const float* b_ih    = (const float*)d_in[7];
    const float* b_hh    = (const float*)d_in[8];
    const float* W_e     = (const float*)d_in[9];
    const float* b_e     = (const float*)d_in[10];
    const float* W_s     = (const float*)d_in[11];
    const float* b_s     = (const float*)d_in[12];

    float* out       = (float*)d_out;
    float* out_emo   = out;                                    // [B,7]
    float* out_shift = out + (size_t)B_SZ * E_SZ;              // [B]
    float* out_mem   = out + (size_t)B_SZ * E_SZ + B_SZ;       // [S,H]

    int*    winner = (int*)d_ws;                               // S ints
    ushort* W2f    = (ushort*)((char*)d_ws + (size_t)S_SZ * sizeof(int));

    hipMemsetAsync(winner, 0xFF, (size_t)S_SZ * sizeof(int), stream);   // -1

    pack_w2f_kernel<<<(NFR * NSTEP * 64 + 255) / 256, 256, 0, stream>>>(
        W_ih, W_hh, b_ih, b_hh, W_e, b_e, W_s, b_s, W2f);
    winner_kernel<<<B_SZ / 256, 256, 0, stream>>>(slot_ids, winner);
    fused_kernel<<<B_SZ / 32, 256, 0, stream>>>(
        h_t, h_ctx, sent, slot_ids, memory, W2f, winner, out_emo, out_shift, out_mem);
}

// Round 12
// 93.232 us; speedup vs baseline: 1.2952x; 1.0722x over previous
//
#include <hip/hip_runtime.h>
#include <hip/hip_bf16.h>

// Problem constants
#define B_SZ   16384
#define D_SZ   768
#define H_SZ   128
#define S_SZ   65536
#define E_SZ   7

// K layout: [0,768) h_t | [768,896) s_t | [896,1664) h_ctx | 1664..1666 sent | 1667 bias | pad->1696
// N layout: [0,256) r,z summed | [256,384) i_n | [384,512) h_n | [512,519) W_e | 519 W_s | pad->528
// Wave w owns hidden j in [32w, 32w+32): frags r {2w,2w+1}, z {8+2w,9+2w}, i_n {16+2w,17+2w},
// h_n {24+2w,25+2w} -> GRU epilogue is wave-local. Heads (frag 32) K-split by (s&3)==w, reduced via LDS.
// A staged in 8-step chunks (32 KB) via global_load_lds, double-buffered; 7 main-loop barriers.
#define NFR    33
#define NSTEP  53

typedef __attribute__((ext_vector_type(8))) short bf16x8;
typedef __attribute__((ext_vector_type(4))) float f32x4;

#define LD4(p) (*reinterpret_cast<const float4*>(p))
#define MFMA(d, a, b) d = __builtin_amdgcn_mfma_f32_16x16x32_bf16(a, b, d, 0, 0, 0)

// async global->LDS DMA, 16B/lane, dest = wave-uniform base + lane*16
#define GLDS(gp, lp) __builtin_amdgcn_global_load_lds(                              \
        (const __attribute__((address_space(1))) unsigned int*)(gp),                \
        (__attribute__((address_space(3))) unsigned int*)(lp), 16, 0, 0)

static __device__ __forceinline__ ushort f2bf(float v) {
    unsigned u = __float_as_uint(v);
    u = (u + 0x7FFFu + ((u >> 16) & 1u)) >> 16;   // RNE (pack kernel / tail only)
    return (ushort)u;
}

static __device__ __forceinline__ unsigned pk2(float x, float y) {
    unsigned a = __float_as_uint(x) + 0x8000u;
    unsigned b = __float_as_uint(y) + 0x8000u;
    return __builtin_amdgcn_perm(b, a, 0x07060302);   // [a.hi16 | b.hi16]
}

static __device__ __forceinline__ bf16x8 cvt8(float4 a, float4 b) {
    union { unsigned u[4]; bf16x8 v; } r;
    r.u[0] = pk2(a.x, a.y); r.u[1] = pk2(a.z, a.w);
    r.u[2] = pk2(b.x, b.y); r.u[3] = pk2(b.z, b.w);
    return r.v;
}

// logical packed-weight value at (n, k)
static __device__ __forceinline__ float w2_value(int n, int k,
    const float* __restrict__ W_ih, const float* __restrict__ W_hh,
    const float* __restrict__ b_ih, const float* __restrict__ b_hh,
    const float* __restrict__ W_e,  const float* __restrict__ b_e,
    const float* __restrict__ W_s,  const float* __restrict__ b_s)
{
    float v = 0.0f;
    if (n < 256) {
        if (k < 768)                        v = W_ih[(size_t)n * 771 + k];
        else if (k < 896)                   v = W_hh[(size_t)n * 128 + (k - 768)];
        else if (k >= 1664 && k < 1667)     v = W_ih[(size_t)n * 771 + 768 + (k - 1664)];
        else if (k == 1667)                 v = b_ih[n] + b_hh[n];
    } else if (n < 384) {
        if (k < 768)                        v = W_ih[(size_t)n * 771 + k];
        else if (k >= 1664 && k < 1667)     v = W_ih[(size_t)n * 771 + 768 + (k - 1664)];
        else if (k == 1667)                 v = b_ih[n];
    } else if (n < 512) {
        int g = n - 128;
        if (k >= 768 && k < 896)            v = W_hh[(size_t)g * 128 + (k - 768)];
        else if (k == 1667)                 v = b_hh[g];
    } else if (n < 520) {
        int e = n - 512;
        const float* Wr = (e < E_SZ) ? (W_e + (size_t)e * 1667) : W_s;
        if (k < 768)                        v = Wr[k];
        else if (k < 896)                   v = Wr[771 + (k - 768)];
        else if (k < 1664)                  v = Wr[899 + (k - 896)];
        else if (k < 1667)                  v = Wr[768 + (k - 1664)];
        else if (k == 1667)                 v = (e < E_SZ) ? b_e[e] : b_s[0];
    }
    return v;
}

// ---------------- pack W2 frag-major: W2f[(nf*NSTEP + kstep)*64 + lane][8] ----------------
__global__ __launch_bounds__(256) void pack_w2f_kernel(
    const float* __restrict__ W_ih, const float* __restrict__ W_hh,
    const float* __restrict__ b_ih, const float* __restrict__ b_hh,
    const float* __restrict__ W_e,  const float* __restrict__ b_e,
    const float* __restrict__ W_s,  const float* __restrict__ b_s,
    ushort* __restrict__ W2f)
{
    int tid = blockIdx.x * 256 + threadIdx.x;
    if (tid >= NFR * NSTEP * 64) return;
    int lane  = tid & 63;
    int kstep = (tid >> 6) % NSTEP;
    int nf    = tid / (NSTEP * 64);
    int n     = nf * 16 + (lane & 15);
    int kbase = kstep * 32 + (lane >> 4) * 8;
    ushort o[8];
#pragma unroll
    for (int j = 0; j < 8; ++j)
        o[j] = f2bf(w2_value(n, kbase + j, W_ih, W_hh, b_ih, b_hh, W_e, b_e, W_s, b_s));
    *reinterpret_cast<uint4*>(W2f + (size_t)tid * 8) = *reinterpret_cast<const uint4*>(o);
}

// ---------------- winner (last-write-wins) ----------------
__global__ __launch_bounds__(256) void winner_kernel(const int* __restrict__ slot_ids,
                                                     int* __restrict__ winner)
{
    int b = blockIdx.x * 256 + threadIdx.x;
    if (b < B_SZ) atomicMax(&winner[slot_ids[b]], b);
}

static __device__ __forceinline__ bf16x8 ldB(const ushort* __restrict__ W2f, int nf, int ks, int lane) {
    return *reinterpret_cast<const bf16x8*>(W2f + ((size_t)(nf * NSTEP + ks) * 64 + lane) * 8);
}

// LDS A read: 8-step panel, XOR-swizzled (matches pre-swizzled DMA source)
static __device__ __forceinline__ float4 lds_rd(const char* Ab, int st, int row, int h) {
    return *reinterpret_cast<const float4*>(Ab + st * 4096 + row * 128 + ((h ^ (row & 7)) << 4));
}

// one GEMM K-step for wave W. KIND 0: h_t (r,z,i_n); KIND 1: s_t (r,z,h_n).
template<int W, int KIND>
static __device__ __forceinline__ void gemm_step(int s, int st, bool hd, const char* Ab, int lane,
                                                 const ushort* __restrict__ W2f,
                                                 f32x4* __restrict__ acc, f32x4* __restrict__ hacc)
{
    const int cl = lane & 15, kg = lane >> 4;
    constexpr int A4 = (KIND == 0) ? 4 : 6;
    constexpr int F4 = (KIND == 0) ? 16 : 24;
    bf16x8 B0 = ldB(W2f, 2 * W, s, lane),      B1 = ldB(W2f, 2 * W + 1, s, lane);
    bf16x8 B2 = ldB(W2f, 8 + 2 * W, s, lane),  B3 = ldB(W2f, 9 + 2 * W, s, lane);
    bf16x8 B4 = ldB(W2f, F4 + 2 * W, s, lane), B5 = ldB(W2f, F4 + 2 * W + 1, s, lane);
    bf16x8 Bh;
    if (hd) Bh = ldB(W2f, 32, s, lane);
    float4 x0 = lds_rd(Ab, st, cl, 2 * kg), x1 = lds_rd(Ab, st, cl, 2 * kg + 1);
    bf16x8 a0 = cvt8(x0, x1);
    MFMA(acc[0], a0, B0); MFMA(acc[1], a0, B1);
    MFMA(acc[2], a0, B2); MFMA(acc[3], a0, B3);
    MFMA(acc[A4], a0, B4); MFMA(acc[A4 + 1], a0, B5);
    if (hd) MFMA(hacc[0], a0, Bh);
    float4 y0 = lds_rd(Ab, st, 16 + cl, 2 * kg), y1 = lds_rd(Ab, st, 16 + cl, 2 * kg + 1);
    bf16x8 a1 = cvt8(y0, y1);
    MFMA(acc[8], a1, B0); MFMA(acc[9], a1, B1);
    MFMA(acc[10], a1, B2); MFMA(acc[11], a1, B3);
    MFMA(acc[8 + A4], a1, B4); MFMA(acc[9 + A4], a1, B5);
    if (hd) MFMA(hacc[1], a1, Bh);
}

template<int W, int C>
static __device__ __forceinline__ void chunk_ht(const char* Ab, int lane,
                                                const ushort* __restrict__ W2f,
                                                f32x4* acc, f32x4* hacc)
{
#pragma unroll
    for (int st = 0; st < 8; ++st)
        gemm_step<W, 0>(C * 8 + st, st, (st & 3) == W, Ab, lane, W2f, acc, hacc);
}

template<int W>
static __device__ __forceinline__ void chunk_st(const char* Ab, int lane,
                                                const ushort* __restrict__ W2f,
                                                f32x4* acc, f32x4* hacc)
{
#pragma unroll
    for (int t = 0; t < 4; ++t)
        gemm_step<W, 1>(24 + t, t, t == W, Ab, lane, W2f, acc, hacc);
}

// heads-only steps (h_ctx phase): wave W handles steps with (s&3)==W
template<int W, int SB, int STB, int N>
static __device__ __forceinline__ void ctx_steps(const char* Ab, int lane,
                                                 const ushort* __restrict__ W2f, f32x4* hacc)
{
    const int cl = lane & 15, kg = lane >> 4;
#pragma unroll
    for (int i = 0; i < N; ++i) {
        if (((SB + i) & 3) == W) {
            bf16x8 Bh = ldB(W2f, 32, SB + i, lane);
            float4 x0 = lds_rd(Ab, STB + i, cl, 2 * kg), x1 = lds_rd(Ab, STB + i, cl, 2 * kg + 1);
            MFMA(hacc[0], cvt8(x0, x1), Bh);
            float4 y0 = lds_rd(Ab, STB + i, 16 + cl, 2 * kg), y1 = lds_rd(Ab, STB + i, 16 + cl, 2 * kg + 1);
            MFMA(hacc[1], cvt8(y0, y1), Bh);
        }
    }
}

// tail step 52 + wave-local GRU epilogue + heads-partial dump
template<int W>
static __device__ __forceinline__ void tail_and_epilogue(
    const float* __restrict__ sent, const float* __restrict__ memory,
    const int* __restrict__ slot_ids, const int* __restrict__ winner,
    int row0, int lane, const ushort* __restrict__ W2f,
    f32x4* __restrict__ acc, f32x4* __restrict__ hacc, f32x4* __restrict__ redh,
    float* __restrict__ out_mem)
{
    const int cl = lane & 15, kg = lane >> 4;
    // tail (k=1664..1695): sent(3) + bias-one + zeros
    {
        const int rA0 = row0 + cl, rA1 = rA0 + 16;
        bf16x8 a0, a1;
#pragma unroll
        for (int jj = 0; jj < 8; ++jj) {
            int kk = kg * 8 + jj;
            float v0 = 0.f, v1 = 0.f;
            if (kk < 3)       { v0 = sent[(size_t)rA0 * 3 + kk]; v1 = sent[(size_t)rA1 * 3 + kk]; }
            else if (kk == 3) { v0 = 1.f; v1 = 1.f; }
            a0[jj] = (short)f2bf(v0); a1[jj] = (short)f2bf(v1);
        }
        bf16x8 T0 = ldB(W2f, 2 * W, 52, lane),      T1 = ldB(W2f, 2 * W + 1, 52, lane);
        bf16x8 T2 = ldB(W2f, 8 + 2 * W, 52, lane),  T3 = ldB(W2f, 9 + 2 * W, 52, lane);
        bf16x8 T4 = ldB(W2f, 16 + 2 * W, 52, lane), T5 = ldB(W2f, 17 + 2 * W, 52, lane);
        bf16x8 T6 = ldB(W2f, 24 + 2 * W, 52, lane), T7 = ldB(W2f, 25 + 2 * W, 52, lane);
        MFMA(acc[0], a0, T0); MFMA(acc[1], a0, T1);
        MFMA(acc[2], a0, T2); MFMA(acc[3], a0, T3);
        MFMA(acc[4], a0, T4); MFMA(acc[5], a0, T5);
        MFMA(acc[6], a0, T6); MFMA(acc[7], a0, T7);
        MFMA(acc[8], a1, T0); MFMA(acc[9], a1, T1);
        MFMA(acc[10], a1, T2); MFMA(acc[11], a1, T3);
        MFMA(acc[12], a1, T4); MFMA(acc[13], a1, T5);
        MFMA(acc[14], a1, T6); MFMA(acc[15], a1, T7);
        if constexpr (W == 0) {   // step 52: (52&3)==0
            bf16x8 Bh = ldB(W2f, 32, 52, lane);
            MFMA(hacc[0], a0, Bh); MFMA(hacc[1], a1, Bh);
        }
    }
    // dump heads partials (read after the following barrier)
    redh[(0 * 4 + W) * 64 + lane] = hacc[0];
    redh[(1 * 4 + W) * 64 + lane] = hacc[1];
    // wave-local GRU + winner scatter for hidden j in [32W, 32W+32)
#pragma unroll
    for (int rg = 0; rg < 2; ++rg) {
#pragma unroll
        for (int r = 0; r < 4; ++r) {
            const int row  = row0 + rg * 16 + kg * 4 + r;
            const int slot = slot_ids[row];
            const bool win = (winner[slot] == row);
#pragma unroll
            for (int jb = 0; jb < 2; ++jb) {
                const int j = 32 * W + jb * 16 + cl;
                float rgate = acc[rg * 8 + jb][r];
                float zg    = acc[rg * 8 + 2 + jb][r];
                float inn   = acc[rg * 8 + 4 + jb][r];
                float hnn   = acc[rg * 8 + 6 + jb][r];
                rgate = 1.0f / (1.0f + __expf(-rgate));
                zg    = 1.0f / (1.0f + __expf(-zg));
                float nn = tanhf(inn + rgate * hnn);
                float h  = memory[(size_t)slot * H_SZ + j];   // exact f32 pre-update state
                float sn = (1.0f - zg) * nn + zg * h;
                if (win) out_mem[(size_t)slot * H_SZ + j] = sn;
            }
        }
    }
}

// ---------------- fused kernel ----------------
__global__ __launch_bounds__(256, 2) void fused_kernel(
    const float* __restrict__ h_t,   const float* __restrict__ h_ctx,
    const float* __restrict__ sent,  const int* __restrict__ slot_ids,
    const float* __restrict__ memory,const ushort* __restrict__ W2f,
    const int* __restrict__ winner,
    float* __restrict__ out_emo, float* __restrict__ out_shift, float* __restrict__ out_mem)
{
    __shared__ alignas(16) char  A_st[2][8 * 4096];   // 64 KB: 2 bufs x 8 steps x [32 rows][128 B]
    __shared__ alignas(16) f32x4 redh[8 * 64];        // 8 KB heads partials

    const int tid  = threadIdx.x;
    const int wave = tid >> 6;
    const int lane = tid & 63;
    const int row0 = blockIdx.x * 32;

    // staging identity: thread -> (row = tid>>3, lds-chunk = tid&7); global chunk pre-swizzled
    const int srow  = tid >> 3;
    const int scg   = (tid & 7) ^ (srow & 7);
    const int sslot = slot_ids[row0 + srow];

    f32x4 acc[16], hacc[2];
    {
        f32x4 z = {0.f, 0.f, 0.f, 0.f};
#pragma unroll
        for (int i = 0; i < 16; ++i) acc[i] = z;
        hacc[0] = z; hacc[1] = z;
    }

#define STAGE_HT(BUF, S0) do { _Pragma("unroll")                                          \
    for (int st = 0; st < 8; ++st)                                                        \
        GLDS(h_t + (size_t)(row0 + srow) * D_SZ + (S0 + st) * 32 + scg * 4,               \
             &A_st[BUF][st * 4096 + wave * 1024]); } while (0)

#define STAGE_MEM(BUF) do { _Pragma("unroll")                                             \
    for (int st = 0; st < 4; ++st)                                                        \
        GLDS(memory + (size_t)sslot * H_SZ + st * 32 + scg * 4,                           \
             &A_st[BUF][st * 4096 + wave * 1024]); } while (0)

#define STAGE_CTX(BUF, X0, STB, N) do { _Pragma("unroll")                                 \
    for (int st = 0; st < (N); ++st)                                                      \
        GLDS(h_ctx + (size_t)(row0 + srow) * D_SZ + ((X0) + st) * 32 + scg * 4,           \
             &A_st[BUF][((STB) + st) * 4096 + wave * 1024]); } while (0)

#define COPYSL(I0, N) do {                                                                \
    for (int k = 0; k < (N); ++k) {                                                       \
        int idx  = ((I0) + k) * 256 + tid;                                                \
        int rr   = idx >> 5;                                                              \
        int c4   = (idx & 31) * 4;                                                        \
        int slot = blockIdx.x * 128 + rr;                                                 \
        if (winner[slot] < 0) {                                                           \
            float4 v = LD4(memory + (size_t)slot * H_SZ + c4);                            \
            *reinterpret_cast<float4*>(out_mem + (size_t)slot * H_SZ + c4) = v;           \
        } } } while (0)

#define BYWAVE(...) do { switch (wave) {                                                  \
    case 0: { constexpr int W = 0; __VA_ARGS__; } break;                                  \
    case 1: { constexpr int W = 1; __VA_ARGS__; } break;                                  \
    case 2: { constexpr int W = 2; __VA_ARGS__; } break;                                  \
    default:{ constexpr int W = 3; __VA_ARGS__; } break; } } while (0)

    // prologue: stage chunk 0 (h_t steps 0-7)
    STAGE_HT(0, 0);
    __syncthreads();

    // iter 0: compute chunk 0 (buf0), stage chunk 1 (buf1)
    STAGE_HT(1, 8);  COPYSL(0, 3);
    BYWAVE(chunk_ht<W, 0>(A_st[0], lane, W2f, acc, hacc));
    __syncthreads();

    // iter 1: chunk 1 (buf1), stage chunk 2
    STAGE_HT(0, 16); COPYSL(3, 3);
    BYWAVE(chunk_ht<W, 1>(A_st[1], lane, W2f, acc, hacc));
    __syncthreads();

    // iter 2: chunk 2 (buf0), stage chunk 3 (mixed: 4 s_t gather + ctx steps 28-31)
    STAGE_MEM(1); STAGE_CTX(1, 0, 4, 4); COPYSL(6, 2);
    BYWAVE(chunk_ht<W, 2>(A_st[0], lane, W2f, acc, hacc));
    __syncthreads();

    // iter 3: chunk 3 (buf1), stage chunk 4 (ctx 32-39)
    STAGE_CTX(0, 4, 0, 8); COPYSL(8, 2);
    BYWAVE((chunk_st<W>(A_st[1], lane, W2f, acc, hacc),
            ctx_steps<W, 28, 4, 4>(A_st[1], lane, W2f, hacc)));
    __syncthreads();

    // iter 4: chunk 4 (buf0), stage chunk 5 (ctx 40-47)
    STAGE_CTX(1, 12, 0, 8); COPYSL(10, 2);
    BYWAVE((ctx_steps<W, 32, 0, 8>(A_st[0], lane, W2f, hacc)));
    __syncthreads();

    // iter 5: chunk 5 (buf1), stage chunk 6 (ctx 48-51, 4 steps)
    STAGE_CTX(0, 20, 0, 4); COPYSL(12, 2);
    BYWAVE((ctx_steps<W, 40, 0, 8>(A_st[1], lane, W2f, hacc)));
    __syncthreads();

    // iter 6: chunk 6 (buf0) + tail + wave-local GRU + heads dump
    COPYSL(14, 2);
    BYWAVE((ctx_steps<W, 48, 0, 4>(A_st[0], lane, W2f, hacc),
            tail_and_epilogue<W>(sent, memory, slot_ids, winner, row0, lane, W2f,
                                 acc, hacc, redh, out_mem)));
    __syncthreads();

    // heads outputs: sum 4 waves' partials
    if (tid < 128) {
        const int rg = tid >> 6, l = tid & 63;
        f32x4 hv = redh[(rg * 4 + 0) * 64 + l];
        hv += redh[(rg * 4 + 1) * 64 + l];
        hv += redh[(rg * 4 + 2) * 64 + l];
        hv += redh[(rg * 4 + 3) * 64 + l];
        const int col  = l & 15;
        const int rowb = row0 + rg * 16 + (l >> 4) * 4;
#pragma unroll
        for (int r = 0; r < 4; ++r) {
            const int row = rowb + r;
            if (col < E_SZ)       out_emo[(size_t)row * E_SZ + col] = hv[r];
            else if (col == E_SZ) out_shift[row] = hv[r];
        }
    }
#undef STAGE_HT
#undef STAGE_MEM
#undef STAGE_CTX
#undef COPYSL
#undef BYWAVE
}

// ---------------- launch ----------------
extern "C" void kernel_launch(void* const* d_in, const int* in_sizes, int n_in,
                              void* d_out, int out_size, void* d_ws, size_t ws_size,
                              hipStream_t stream)
{
    const float* h_t     = (const float*)d_in[0];
    const float* h_ctx   = (const float*)d_in[1];
    const float* sent    = (const float*)d_in[2];
    const int*   slot_ids= (const int*)  d_in[3];
    const float* memory  = (const float*)d_in[4];
    const float* W_ih    = (const float*)d_in[5];
    const float* W_hh    = (const float*)d_in[6];
    const float* b_ih    = (const float*)d_in[7];
    const float* b_hh    = (const float*)d_in[8];
    const float* W_e     = (const float*)d_in[9];
    const float* b_e     = (const float*)d_in[10];
    const float* W_s     = (const float*)d_in[11];
    const float* b_s     = (const float*)d_in[12];

    float* out       = (float*)d_out;
    float* out_emo   = out;                                    // [B,7]
    float* out_shift = out + (size_t)B_SZ * E_SZ;              // [B]
    float* out_mem   = out + (size_t)B_SZ * E_SZ + B_SZ;       // [S,H]

    int*    winner = (int*)d_ws;                               // S ints
    ushort* W2f    = (ushort*)((char*)d_ws + (size_t)S_SZ * sizeof(int));

    hipMemsetAsync(winner, 0xFF, (size_t)S_SZ * sizeof(int), stream);   // -1

    pack_w2f_kernel<<<(NFR * NSTEP * 64 + 255) / 256, 256, 0, stream>>>(
        W_ih, W_hh, b_ih, b_hh, W_e, b_e, W_s, b_s, W2f);
    winner_kernel<<<B_SZ / 256, 256, 0, stream>>>(slot_ids, winner);
    fused_kernel<<<B_SZ / 32, 256, 0, stream>>>(
        h_t, h_ctx, sent, slot_ids, memory, W2f, winner, out_emo, out_shift, out_mem);
}